// Round 12
// baseline (283.653 us; speedup 1.0000x reference)
//
#include <hip/hip_runtime.h>
#include <cstdint>
#include <climits>
#include <cstddef>

typedef unsigned long long u64;

#define B_ROWS 65536
#define BN_EPS 1e-5

// ---------------------------------------------------------------------------
// R7/R11-proven structure (202.7us, absmax=0). Single change this round:
// layer_mid tiling 512thr/128rows/512blk -> 256thr/64rows/1024blk for
// higher block-level phase overlap (R6->R7 layer4 mechanism).
// Layouts (float4-interleaved, verified absmax=0 rounds 3-11):
//   x/layer0 A: 13 words/row. word k=4*cg+e (cg<3): bit l <-> col cg*256+4l+e.
//               word 12: cols 768..783 as 4 nibbles.
//   layers 1..4 A: 4 words, word e: bit l <-> col 4l+e.
//   Weights in E-PLANE layout: wbXp[((c&7)*KW + k)*32 + (c>>3)].
//   w4b[c*4+e] interleaved words (broadcast reads).
//   bitsx col-major [word][row]; v int16 [row][256] (uint4 stores);
//   v4 int16 [row][10].
// ---------------------------------------------------------------------------

// ---------------------------------------------------------------------------
// prep_all: pack x (blocks 0..2047), w0 (2048..2111), w1..w4 (2112..2306),
// zero stats (2307). Mostly HBM-bound on x.
// ---------------------------------------------------------------------------
__global__ __launch_bounds__(256) void prep_all(
    const float* __restrict__ x, const float* __restrict__ w0,
    const float* __restrict__ w1, const float* __restrict__ w2,
    const float* __restrict__ w3, const float* __restrict__ w4,
    u64* __restrict__ bitsx, u64* __restrict__ wb0p, u64* __restrict__ wbTp,
    u64* __restrict__ w4b,
    long long* gsum, long long* gsq, int* gmin, int* gmax, double* colsum)
{
    const int lane = threadIdx.x & 63;
    const int wv   = threadIdx.x >> 6;
    const int b    = blockIdx.x;

    if (b < 2048) {
        // ---- x pack: wave per 8 rows ----
        const int gw = b * 4 + wv;
        for (int i = 0; i < 8; ++i) {
            const int row = gw * 8 + i;
            const float4* xr = (const float4*)(x + (size_t)row * 784);
#pragma unroll
            for (int cg = 0; cg < 3; ++cg) {
                const float4 f = xr[cg*64 + lane];
                const u64 e0 = __ballot(f.x >= 0.5f);
                const u64 e1 = __ballot(f.y >= 0.5f);
                const u64 e2 = __ballot(f.z >= 0.5f);
                const u64 e3 = __ballot(f.w >= 0.5f);
                if (lane == 0) {
                    bitsx[(size_t)(cg*4+0)*65536 + row] = e0;
                    bitsx[(size_t)(cg*4+1)*65536 + row] = e1;
                    bitsx[(size_t)(cg*4+2)*65536 + row] = e2;
                    bitsx[(size_t)(cg*4+3)*65536 + row] = e3;
                }
            }
            float4 f = make_float4(-1.f, -1.f, -1.f, -1.f);
            if (lane < 4) f = xr[192 + lane];
            const u64 e0 = __ballot(f.x >= 0.5f) & 0xF;
            const u64 e1 = __ballot(f.y >= 0.5f) & 0xF;
            const u64 e2 = __ballot(f.z >= 0.5f) & 0xF;
            const u64 e3 = __ballot(f.w >= 0.5f) & 0xF;
            if (lane == 0)
                bitsx[(size_t)12*65536 + row] = e0 | (e1 << 4) | (e2 << 8) | (e3 << 12);
        }
    } else if (b < 2112) {
        // ---- w0 pack -> e-plane layout ----
        const int c = (b - 2048) * 4 + wv;
        const int pb = (c & 7) * 13;      // plane base
        const int g  = c >> 3;            // col group
        const float4* row = (const float4*)(w0 + (size_t)c * 784);
#pragma unroll
        for (int cg = 0; cg < 3; ++cg) {
            const float4 f = row[cg*64 + lane];
            const u64 e0 = __ballot(f.x >= 0.0f);
            const u64 e1 = __ballot(f.y >= 0.0f);
            const u64 e2 = __ballot(f.z >= 0.0f);
            const u64 e3 = __ballot(f.w >= 0.0f);
            if (lane == 0) {
                wb0p[(pb + cg*4+0)*32 + g] = e0;
                wb0p[(pb + cg*4+1)*32 + g] = e1;
                wb0p[(pb + cg*4+2)*32 + g] = e2;
                wb0p[(pb + cg*4+3)*32 + g] = e3;
            }
        }
        float4 f = make_float4(-1.f, -1.f, -1.f, -1.f);
        if (lane < 4) f = row[192 + lane];
        const u64 e0 = __ballot(f.x >= 0.0f) & 0xF;
        const u64 e1 = __ballot(f.y >= 0.0f) & 0xF;
        const u64 e2 = __ballot(f.z >= 0.0f) & 0xF;
        const u64 e3 = __ballot(f.w >= 0.0f) & 0xF;
        if (lane == 0) wb0p[(pb + 12)*32 + g] = e0 | (e1 << 4) | (e2 << 8) | (e3 << 12);
    } else if (b < 2307) {
        // ---- w1..w3 -> e-plane; w4 -> w4b[c*4+e] ----
        const int idx = (b - 2112) * 4 + wv;         // 0..779
        if (idx < 768) {
            const int L = idx >> 8, c = idx & 255;
            const float* ws = (L == 0) ? w1 : (L == 1) ? w2 : w3;
            const float4 f = *(const float4*)(ws + (size_t)c * 256 + 4*lane);
            const u64 e0 = __ballot(f.x >= 0.0f);
            const u64 e1 = __ballot(f.y >= 0.0f);
            const u64 e2 = __ballot(f.z >= 0.0f);
            const u64 e3 = __ballot(f.w >= 0.0f);
            if (lane == 0) {
                const int pb = (c & 7) * 4;
                const int g  = c >> 3;
                wbTp[L*1024 + (pb+0)*32 + g] = e0;
                wbTp[L*1024 + (pb+1)*32 + g] = e1;
                wbTp[L*1024 + (pb+2)*32 + g] = e2;
                wbTp[L*1024 + (pb+3)*32 + g] = e3;
            }
        } else if (idx < 778) {
            const int c = idx - 768;
            const float4 f = *(const float4*)(w4 + (size_t)c * 256 + 4*lane);
            const u64 e0 = __ballot(f.x >= 0.0f);
            const u64 e1 = __ballot(f.y >= 0.0f);
            const u64 e2 = __ballot(f.z >= 0.0f);
            const u64 e3 = __ballot(f.w >= 0.0f);
            if (lane == 0) {
                w4b[c*4+0] = e0; w4b[c*4+1] = e1; w4b[c*4+2] = e2; w4b[c*4+3] = e3;
            }
        }
    } else {
        for (int i = threadIdx.x; i < 1040; i += 256) { gsum[i] = 0; gsq[i] = 0; }
        if (threadIdx.x < 16) {
            gmin[threadIdx.x] = INT_MAX;
            gmax[threadIdx.x] = INT_MIN;
            colsum[threadIdx.x] = 0.0;
        }
    }
}

// ---------------------------------------------------------------------------
// bn_threshold: exact integer binarization threshold from exact stats.
// ---------------------------------------------------------------------------
__device__ __forceinline__ void bn_threshold(long long sv, long long qv,
    float gaf, float bef, int& sg, int& t)
{
    const double mean = (double)sv / (double)B_ROWS;
    double var = (double)qv / (double)B_ROWS - mean * mean;
    if (var < 0.0) var = 0.0;
    const double rs    = 1.0 / sqrt(var + BN_EPS);
    const double scale = (double)gaf * rs;
    const double bt    = (double)bef;
    if (scale > 0.0) {
        const double tt = fmin(fmax(mean - bt / scale, -1e6), 1e6);
        sg = 1; t = (int)ceil(tt);
    } else if (scale < 0.0) {
        const double tt = fmin(fmax(mean - bt / scale, -1e6), 1e6);
        sg = -1; t = (int)(-floor(tt));
    } else { sg = 0; t = (bt >= 0.0) ? INT_MIN : 1; }
}

// ---------------------------------------------------------------------------
// gemm_coal: 128 rows x 256 cols popcount GEMM (512 thr), coalesced v stores.
// (R7-proven, used by layer0.) ct=tid&31 cols 8ct..+7; rt=tid>>5 rows rt+16j.
// ---------------------------------------------------------------------------
template<int KW>
__device__ __forceinline__ void gemm_coal(const u64* __restrict__ sA,
    const u64* __restrict__ sWp, int K, int row0,
    short* __restrict__ vout, long long* gsumL, long long* gsqL,
    int* sS, int* sQ)
{
    const int tid = threadIdx.x;
    const int ct  = tid & 31;
    const int rt  = tid >> 5;          // 0..15

    unsigned p2[8][4];                 // [row j][colpair e2]
#pragma unroll
    for (int j = 0; j < 8; ++j)
#pragma unroll
        for (int e2 = 0; e2 < 4; ++e2) p2[j][e2] = 0;

#pragma unroll 1
    for (int k = 0; k < KW; ++k) {
        u64 a[8];
#pragma unroll
        for (int j = 0; j < 8; ++j) a[j] = sA[k*128 + rt + 16*j];
        u64 w[8];
#pragma unroll
        for (int e = 0; e < 8; ++e) w[e] = sWp[(e*KW + k)*32 + ct];
#pragma unroll
        for (int j = 0; j < 8; ++j)
#pragma unroll
            for (int e2 = 0; e2 < 4; ++e2)
                p2[j][e2] += (unsigned)__popcll(a[j] ^ w[2*e2])
                           + ((unsigned)__popcll(a[j] ^ w[2*e2+1]) << 16);
    }

    int s8[8], q8[8];
#pragma unroll
    for (int e = 0; e < 8; ++e) { s8[e] = 0; q8[e] = 0; }

#pragma unroll
    for (int j = 0; j < 8; ++j) {
        const int r = row0 + rt + 16*j;
        unsigned pk[4];
#pragma unroll
        for (int e2 = 0; e2 < 4; ++e2) {
            const int v0 = K - 2 * (int)(p2[j][e2] & 0xFFFFu);
            const int v1 = K - 2 * (int)(p2[j][e2] >> 16);
            s8[2*e2]   += v0; q8[2*e2]   += v0*v0;
            s8[2*e2+1] += v1; q8[2*e2+1] += v1*v1;
            pk[e2] = (unsigned)(unsigned short)(short)v0
                   | ((unsigned)(unsigned short)(short)v1 << 16);
        }
        *(uint4*)(vout + (size_t)r * 256 + 8*ct) = make_uint4(pk[0], pk[1], pk[2], pk[3]);
    }

#pragma unroll
    for (int e = 0; e < 8; ++e) {
        s8[e] += __shfl_xor(s8[e], 32);
        q8[e] += __shfl_xor(q8[e], 32);
    }
    if ((tid & 63) < 32) {
#pragma unroll
        for (int e = 0; e < 8; ++e) {
            atomicAdd(&sS[8*ct + e], s8[e]);
            atomicAdd(&sQ[8*ct + e], q8[e]);
        }
    }
    __syncthreads();
    if (tid < 256) {
        atomicAdd((u64*)&gsumL[tid], (u64)(long long)sS[tid]);
        atomicAdd((u64*)&gsqL[tid],  (u64)(long long)sQ[tid]);
    }
}

// ---------------------------------------------------------------------------
// gemm_coal64: 64 rows x 256 cols popcount GEMM (256 thr), coalesced stores.
// ct=tid&31 cols 8ct..+7; rt=tid>>5 (0..7) rows rt+8j (j<8). Same wave-local
// stats fold as gemm_coal (shfl_xor(32) merges lane l / l+32, same ct).
// ---------------------------------------------------------------------------
template<int KW>
__device__ __forceinline__ void gemm_coal64(const u64* __restrict__ sA,
    const u64* __restrict__ sWp, int K, int row0,
    short* __restrict__ vout, long long* gsumL, long long* gsqL,
    int* sS, int* sQ)
{
    const int tid = threadIdx.x;
    const int ct  = tid & 31;
    const int rt  = tid >> 5;          // 0..7

    unsigned p2[8][4];
#pragma unroll
    for (int j = 0; j < 8; ++j)
#pragma unroll
        for (int e2 = 0; e2 < 4; ++e2) p2[j][e2] = 0;

#pragma unroll 1
    for (int k = 0; k < KW; ++k) {
        u64 a[8];
#pragma unroll
        for (int j = 0; j < 8; ++j) a[j] = sA[k*64 + rt + 8*j];
        u64 w[8];
#pragma unroll
        for (int e = 0; e < 8; ++e) w[e] = sWp[(e*KW + k)*32 + ct];
#pragma unroll
        for (int j = 0; j < 8; ++j)
#pragma unroll
            for (int e2 = 0; e2 < 4; ++e2)
                p2[j][e2] += (unsigned)__popcll(a[j] ^ w[2*e2])
                           + ((unsigned)__popcll(a[j] ^ w[2*e2+1]) << 16);
    }

    int s8[8], q8[8];
#pragma unroll
    for (int e = 0; e < 8; ++e) { s8[e] = 0; q8[e] = 0; }

#pragma unroll
    for (int j = 0; j < 8; ++j) {
        const int r = row0 + rt + 8*j;
        unsigned pk[4];
#pragma unroll
        for (int e2 = 0; e2 < 4; ++e2) {
            const int v0 = K - 2 * (int)(p2[j][e2] & 0xFFFFu);
            const int v1 = K - 2 * (int)(p2[j][e2] >> 16);
            s8[2*e2]   += v0; q8[2*e2]   += v0*v0;
            s8[2*e2+1] += v1; q8[2*e2+1] += v1*v1;
            pk[e2] = (unsigned)(unsigned short)(short)v0
                   | ((unsigned)(unsigned short)(short)v1 << 16);
        }
        *(uint4*)(vout + (size_t)r * 256 + 8*ct) = make_uint4(pk[0], pk[1], pk[2], pk[3]);
    }

#pragma unroll
    for (int e = 0; e < 8; ++e) {
        s8[e] += __shfl_xor(s8[e], 32);
        q8[e] += __shfl_xor(q8[e], 32);
    }
    if ((tid & 63) < 32) {
#pragma unroll
        for (int e = 0; e < 8; ++e) {
            atomicAdd(&sS[8*ct + e], s8[e]);
            atomicAdd(&sQ[8*ct + e], q8[e]);
        }
    }
    __syncthreads();
    atomicAdd((u64*)&gsumL[tid], (u64)(long long)sS[tid]);
    atomicAdd((u64*)&gsqL[tid],  (u64)(long long)sQ[tid]);
}

// ---------------------------------------------------------------------------
// layer0_kernel: stage bitsx tile + w0 e-planes, GEMM, stats, coalesced v.
// (R7-proven, unchanged.)
// ---------------------------------------------------------------------------
__global__ __launch_bounds__(512, 4) void layer0_kernel(
    const u64* __restrict__ bitsx, const u64* __restrict__ wb0p,
    short* __restrict__ v, long long* gsum, long long* gsq)
{
    __shared__ __align__(16) u64 sA[13*128];
    __shared__ __align__(16) u64 sWp[13*8*32];
    __shared__ int sS[256], sQ[256];
    const int tid  = threadIdx.x;
    const int row0 = blockIdx.x * 128;
    for (int i = tid; i < 13*128; i += 512)
        sA[i] = bitsx[(size_t)(i >> 7)*65536 + row0 + (i & 127)];
    for (int i = tid; i < 13*8*32; i += 512) sWp[i] = wb0p[i];
    if (tid < 256) { sS[tid] = 0; sQ[tid] = 0; }
    __syncthreads();
    gemm_coal<13>(sA, sWp, 784, row0, v, gsum, gsq, sS, sQ);
}

// ---------------------------------------------------------------------------
// layer_mid_kernel v2: 64-row tiles, 256 threads, 1024 blocks (~8 blocks/CU)
// for cross-block phase overlap. thresholds -> rebinarize v in-LDS -> GEMM
// -> stats -> v in place. Math identical to R7's 128-row version.
// ---------------------------------------------------------------------------
__global__ __launch_bounds__(256, 8) void layer_mid_kernel(
    short* v,
    const long long* __restrict__ gsumP, const long long* __restrict__ gsqP,
    const float* __restrict__ gaP, const float* __restrict__ beP,
    const u64* __restrict__ wbTpL, long long* gsumC, long long* gsqC)
{
    __shared__ __align__(16) u64 sA[4*64];
    __shared__ __align__(16) u64 sWp[4*8*32];
    __shared__ int sSgn[256], sThr[256];
    __shared__ int sS[256], sQ[256];
    const int tid  = threadIdx.x;
    const int lane = tid & 63;
    const int wv   = tid >> 6;          // 0..3
    const int row0 = blockIdx.x * 64;

    for (int i = tid; i < 4*8*32; i += 256) sWp[i] = wbTpL[i];
    {
        int sg, t;
        bn_threshold(gsumP[tid], gsqP[tid], gaP[tid], beP[tid], sg, t);
        sSgn[tid] = sg; sThr[tid] = t;
        sS[tid] = 0; sQ[tid] = 0;
    }
    __syncthreads();

    const int4 sg4 = *(const int4*)&sSgn[4*lane];
    const int4 th4 = *(const int4*)&sThr[4*lane];
#pragma unroll 2
    for (int i = 0; i < 16; ++i) {
        const int r = wv * 16 + i;          // 0..63
        const short4 vv = *(const short4*)(v + (size_t)(row0 + r)*256 + 4*lane);
        const u64 e0 = __ballot(sg4.x * (int)vv.x >= th4.x);
        const u64 e1 = __ballot(sg4.y * (int)vv.y >= th4.y);
        const u64 e2 = __ballot(sg4.z * (int)vv.z >= th4.z);
        const u64 e3 = __ballot(sg4.w * (int)vv.w >= th4.w);
        if (lane == 0) {
            sA[0*64 + r] = e0; sA[1*64 + r] = e1;
            sA[2*64 + r] = e2; sA[3*64 + r] = e3;
        }
    }
    __syncthreads();
    gemm_coal64<4>(sA, sWp, 256, row0, v, gsumC, gsqC, sS, sQ);
}

// ---------------------------------------------------------------------------
// layer4_kernel v2 (R7-proven): 512 x 512 = 4096 waves, 16 rows/wave, no LDS
// round-trip: ballots -> lane c<10 popcounts class c -> v4 + exact stats.
// ---------------------------------------------------------------------------
__global__ __launch_bounds__(512) void layer4_kernel(
    const short* __restrict__ v,
    const long long* __restrict__ gsumP, const long long* __restrict__ gsqP,
    const float* __restrict__ gaP, const float* __restrict__ beP,
    const u64* __restrict__ w4b, short* __restrict__ v4,
    long long* gsum4, long long* gsq4, int* gmin, int* gmax)
{
    __shared__ int sSgn[256], sThr[256];
    __shared__ int sS[10], sQ[10], sMn[10], sMx[10];
    const int tid  = threadIdx.x;
    const int lane = tid & 63;
    const int wv   = tid >> 6;          // 0..7

    if (tid < 256) {
        int sg, t;
        bn_threshold(gsumP[tid], gsqP[tid], gaP[tid], beP[tid], sg, t);
        sSgn[tid] = sg; sThr[tid] = t;
    }
    if (tid < 10) { sS[tid] = 0; sQ[tid] = 0; sMn[tid] = INT_MAX; sMx[tid] = INT_MIN; }
    __syncthreads();

    const int4 sg4 = *(const int4*)&sSgn[4*lane];
    const int4 th4 = *(const int4*)&sThr[4*lane];

    u64 wc0 = 0, wc1 = 0, wc2 = 0, wc3 = 0;
    if (lane < 10) {
        wc0 = w4b[lane*4+0]; wc1 = w4b[lane*4+1];
        wc2 = w4b[lane*4+2]; wc3 = w4b[lane*4+3];
    }

    int accS = 0, accQ = 0, mn = INT_MAX, mx = INT_MIN;
    const int waveId = blockIdx.x * 8 + wv;           // 0..4095
    const int r0 = waveId * 16;
#pragma unroll 2
    for (int i = 0; i < 16; ++i) {
        const int r = r0 + i;
        const short4 vv = *(const short4*)(v + (size_t)r*256 + 4*lane);
        const u64 e0 = __ballot(sg4.x * (int)vv.x >= th4.x);
        const u64 e1 = __ballot(sg4.y * (int)vv.y >= th4.y);
        const u64 e2 = __ballot(sg4.z * (int)vv.z >= th4.z);
        const u64 e3 = __ballot(sg4.w * (int)vv.w >= th4.w);
        if (lane < 10) {
            const int p = (int)__popcll(e0 ^ wc0) + (int)__popcll(e1 ^ wc1)
                        + (int)__popcll(e2 ^ wc2) + (int)__popcll(e3 ^ wc3);
            const int vr = 256 - 2*p;
            v4[(size_t)r*10 + lane] = (short)vr;
            accS += vr; accQ += vr*vr;
            mn = min(mn, vr); mx = max(mx, vr);
        }
    }
    if (lane < 10) {
        atomicAdd(&sS[lane], accS);
        atomicAdd(&sQ[lane], accQ);
        atomicMin(&sMn[lane], mn);
        atomicMax(&sMx[lane], mx);
    }
    __syncthreads();
    if (tid < 10) {
        atomicAdd((u64*)&gsum4[tid], (u64)(long long)sS[tid]);
        atomicAdd((u64*)&gsq4[tid],  (u64)(long long)sQ[tid]);
        atomicMin(&gmin[tid], sMn[tid]);
        atomicMax(&gmax[tid], sMx[tid]);
    }
}

// ---------------------------------------------------------------------------
// colsum_kernel: zs/zb (exact from integer min/max) + partial exp-sums.
// ---------------------------------------------------------------------------
__global__ __launch_bounds__(256) void colsum_kernel(
    const short* __restrict__ v4,
    const long long* __restrict__ gsum4, const long long* __restrict__ gsq4,
    const int* __restrict__ gmin, const int* __restrict__ gmax,
    const float* __restrict__ g4, const float* __restrict__ b4,
    double* zsg, double* zbg, double* colsum)
{
    __shared__ double sred[256];
    __shared__ double sZ[2];
    const int c     = blockIdx.x % 10;
    const int chunk = blockIdx.x / 10;
    const int tid   = threadIdx.x;
    if (tid == 0) {
        const double mean = (double)gsum4[c] / (double)B_ROWS;
        double var = (double)gsq4[c] / (double)B_ROWS - mean * mean;
        if (var < 0.0) var = 0.0;
        const double rs    = 1.0 / sqrt(var + BN_EPS);
        const double scale = (double)g4[c] * rs;
        const double bias  = (double)b4[c] - mean * scale;
        const double z1 = scale * (double)gmin[c] + bias;
        const double z2 = scale * (double)gmax[c] + bias;
        const double zb = bias - fmax(z1, z2);
        sZ[0] = scale; sZ[1] = zb;
        zsg[c] = scale; zbg[c] = zb;       // redundant identical writes, benign
    }
    __syncthreads();
    const double zs = sZ[0], zb = sZ[1];
    double acc = 0.0;
    const int r0 = chunk * 1024;
#pragma unroll
    for (int j = 0; j < 4; ++j) {
        const int r = r0 + j*256 + tid;
        acc += (double)expf((float)(zs * (double)v4[(size_t)r*10 + c] + zb));
    }
    sred[tid] = acc; __syncthreads();
    for (int s = 128; s > 0; s >>= 1) {
        if (tid < s) sred[tid] += sred[tid + s];
        __syncthreads();
    }
    if (tid == 0) atomicAdd(&colsum[c], sred[0]);
}

// ---------------------------------------------------------------------------
// out_kernel: out = expf(zs*v + zb) / colsum, coalesced.
// ---------------------------------------------------------------------------
__global__ __launch_bounds__(256) void out_kernel(
    const short* __restrict__ v4, const double* __restrict__ zsg,
    const double* __restrict__ zbg, const double* __restrict__ colsum,
    float* __restrict__ out)
{
    const int idx = blockIdx.x * 256 + threadIdx.x;
    if (idx >= B_ROWS * 10) return;
    const int c = idx % 10;
    const float e = expf((float)(zsg[c] * (double)v4[idx] + zbg[c]));
    out[idx] = (float)((double)e / colsum[c]);
}

// ---------------------------------------------------------------------------
extern "C" void kernel_launch(void* const* d_in, const int* in_sizes, int n_in,
                              void* d_out, int out_size, void* d_ws, size_t ws_size,
                              hipStream_t stream)
{
    const float* x  = (const float*)d_in[0];
    const float* w0 = (const float*)d_in[1];
    const float* g0 = (const float*)d_in[2];
    const float* b0 = (const float*)d_in[3];
    const float* w1 = (const float*)d_in[4];
    const float* g1 = (const float*)d_in[5];
    const float* b1 = (const float*)d_in[6];
    const float* w2 = (const float*)d_in[7];
    const float* g2 = (const float*)d_in[8];
    const float* b2 = (const float*)d_in[9];
    const float* w3 = (const float*)d_in[10];
    const float* g3 = (const float*)d_in[11];
    const float* b3 = (const float*)d_in[12];
    const float* w4 = (const float*)d_in[13];
    const float* g4 = (const float*)d_in[14];
    const float* b4 = (const float*)d_in[15];

    char* p = (char*)d_ws;
    auto alloc = [&](size_t bytes) -> char* {
        char* r = p;
        p += (bytes + 255) & ~(size_t)255;
        return r;
    };
    u64*       bitsx  = (u64*)alloc(13ull*65536*8);
    u64*       wb0p   = (u64*)alloc(13*8*32*8);
    u64*       wbTp   = (u64*)alloc(3*1024*8);
    u64*       w4b    = (u64*)alloc(40*8);
    short*     v      = (short*)alloc(65536ull*256*2);
    short*     v4     = (short*)alloc(65536ull*10*2);
    long long* gsum   = (long long*)alloc(1040*8);
    long long* gsq    = (long long*)alloc(1040*8);
    int*       gmin   = (int*)alloc(16*4);
    int*       gmax   = (int*)alloc(16*4);
    double*    colsum = (double*)alloc(16*8);
    double*    zsg    = (double*)alloc(16*8);
    double*    zbg    = (double*)alloc(16*8);
    float*     out    = (float*)d_out;

    long long* gsum4 = gsum + 1024;
    long long* gsq4  = gsq  + 1024;

    prep_all<<<2308, 256, 0, stream>>>(x, w0, w1, w2, w3, w4,
                                       bitsx, wb0p, wbTp, w4b,
                                       gsum, gsq, gmin, gmax, colsum);

    layer0_kernel<<<512, 512, 0, stream>>>(bitsx, wb0p, v, gsum, gsq);

    layer_mid_kernel<<<1024, 256, 0, stream>>>(v, gsum, gsq, g0, b0,
                                               wbTp + 0*1024, gsum + 256, gsq + 256);
    layer_mid_kernel<<<1024, 256, 0, stream>>>(v, gsum + 256, gsq + 256, g1, b1,
                                               wbTp + 1*1024, gsum + 512, gsq + 512);
    layer_mid_kernel<<<1024, 256, 0, stream>>>(v, gsum + 512, gsq + 512, g2, b2,
                                               wbTp + 2*1024, gsum + 768, gsq + 768);

    layer4_kernel<<<512, 512, 0, stream>>>(v, gsum + 768, gsq + 768, g3, b3,
                                           w4b, v4, gsum4, gsq4, gmin, gmax);

    colsum_kernel<<<640, 256, 0, stream>>>(v4, gsum4, gsq4, gmin, gmax, g4, b4,
                                           zsg, zbg, colsum);

    out_kernel<<<2560, 256, 0, stream>>>(v4, zsg, zbg, colsum, out);
}

// Round 13
// 225.380 us; speedup vs baseline: 1.2586x; 1.2586x over previous
//
#include <hip/hip_runtime.h>
#include <cstdint>
#include <climits>
#include <cstddef>

typedef unsigned long long u64;

#define B_ROWS 65536
#define BN_EPS 1e-5

// ---------------------------------------------------------------------------
// R11-proven structure (202.7us, absmax=0). Single change vs R11: mids at
// 64rows/256thr/1024blk with launch_bounds(256,4) — the R12 experiment with
// the VGPR-spill confound removed (R12's (256,8) capped VGPR at 64 < ~95
// needed -> scratch spill, +80us; (256,4) caps at 128, no spill).
// Layouts (float4-interleaved, verified absmax=0 rounds 3-12):
//   x/layer0 A: 13 words/row. word k=4*cg+e (cg<3): bit l <-> col cg*256+4l+e.
//               word 12: cols 768..783 as 4 nibbles.
//   layers 1..4 A: 4 words, word e: bit l <-> col 4l+e.
//   Weights in E-PLANE layout: wbXp[((c&7)*KW + k)*32 + (c>>3)].
//   w4b[c*4+e] interleaved words (broadcast reads).
//   bitsx col-major [word][row]; v int16 [row][256] (uint4 stores);
//   v4 int16 [row][10].
// ---------------------------------------------------------------------------

// ---------------------------------------------------------------------------
// prep_all: pack x (blocks 0..2047), w0 (2048..2111), w1..w4 (2112..2306),
// zero stats (2307). Mostly HBM-bound on x.
// ---------------------------------------------------------------------------
__global__ __launch_bounds__(256) void prep_all(
    const float* __restrict__ x, const float* __restrict__ w0,
    const float* __restrict__ w1, const float* __restrict__ w2,
    const float* __restrict__ w3, const float* __restrict__ w4,
    u64* __restrict__ bitsx, u64* __restrict__ wb0p, u64* __restrict__ wbTp,
    u64* __restrict__ w4b,
    long long* gsum, long long* gsq, int* gmin, int* gmax, double* colsum)
{
    const int lane = threadIdx.x & 63;
    const int wv   = threadIdx.x >> 6;
    const int b    = blockIdx.x;

    if (b < 2048) {
        // ---- x pack: wave per 8 rows ----
        const int gw = b * 4 + wv;
        for (int i = 0; i < 8; ++i) {
            const int row = gw * 8 + i;
            const float4* xr = (const float4*)(x + (size_t)row * 784);
#pragma unroll
            for (int cg = 0; cg < 3; ++cg) {
                const float4 f = xr[cg*64 + lane];
                const u64 e0 = __ballot(f.x >= 0.5f);
                const u64 e1 = __ballot(f.y >= 0.5f);
                const u64 e2 = __ballot(f.z >= 0.5f);
                const u64 e3 = __ballot(f.w >= 0.5f);
                if (lane == 0) {
                    bitsx[(size_t)(cg*4+0)*65536 + row] = e0;
                    bitsx[(size_t)(cg*4+1)*65536 + row] = e1;
                    bitsx[(size_t)(cg*4+2)*65536 + row] = e2;
                    bitsx[(size_t)(cg*4+3)*65536 + row] = e3;
                }
            }
            float4 f = make_float4(-1.f, -1.f, -1.f, -1.f);
            if (lane < 4) f = xr[192 + lane];
            const u64 e0 = __ballot(f.x >= 0.5f) & 0xF;
            const u64 e1 = __ballot(f.y >= 0.5f) & 0xF;
            const u64 e2 = __ballot(f.z >= 0.5f) & 0xF;
            const u64 e3 = __ballot(f.w >= 0.5f) & 0xF;
            if (lane == 0)
                bitsx[(size_t)12*65536 + row] = e0 | (e1 << 4) | (e2 << 8) | (e3 << 12);
        }
    } else if (b < 2112) {
        // ---- w0 pack -> e-plane layout ----
        const int c = (b - 2048) * 4 + wv;
        const int pb = (c & 7) * 13;      // plane base
        const int g  = c >> 3;            // col group
        const float4* row = (const float4*)(w0 + (size_t)c * 784);
#pragma unroll
        for (int cg = 0; cg < 3; ++cg) {
            const float4 f = row[cg*64 + lane];
            const u64 e0 = __ballot(f.x >= 0.0f);
            const u64 e1 = __ballot(f.y >= 0.0f);
            const u64 e2 = __ballot(f.z >= 0.0f);
            const u64 e3 = __ballot(f.w >= 0.0f);
            if (lane == 0) {
                wb0p[(pb + cg*4+0)*32 + g] = e0;
                wb0p[(pb + cg*4+1)*32 + g] = e1;
                wb0p[(pb + cg*4+2)*32 + g] = e2;
                wb0p[(pb + cg*4+3)*32 + g] = e3;
            }
        }
        float4 f = make_float4(-1.f, -1.f, -1.f, -1.f);
        if (lane < 4) f = row[192 + lane];
        const u64 e0 = __ballot(f.x >= 0.0f) & 0xF;
        const u64 e1 = __ballot(f.y >= 0.0f) & 0xF;
        const u64 e2 = __ballot(f.z >= 0.0f) & 0xF;
        const u64 e3 = __ballot(f.w >= 0.0f) & 0xF;
        if (lane == 0) wb0p[(pb + 12)*32 + g] = e0 | (e1 << 4) | (e2 << 8) | (e3 << 12);
    } else if (b < 2307) {
        // ---- w1..w3 -> e-plane; w4 -> w4b[c*4+e] ----
        const int idx = (b - 2112) * 4 + wv;         // 0..779
        if (idx < 768) {
            const int L = idx >> 8, c = idx & 255;
            const float* ws = (L == 0) ? w1 : (L == 1) ? w2 : w3;
            const float4 f = *(const float4*)(ws + (size_t)c * 256 + 4*lane);
            const u64 e0 = __ballot(f.x >= 0.0f);
            const u64 e1 = __ballot(f.y >= 0.0f);
            const u64 e2 = __ballot(f.z >= 0.0f);
            const u64 e3 = __ballot(f.w >= 0.0f);
            if (lane == 0) {
                const int pb = (c & 7) * 4;
                const int g  = c >> 3;
                wbTp[L*1024 + (pb+0)*32 + g] = e0;
                wbTp[L*1024 + (pb+1)*32 + g] = e1;
                wbTp[L*1024 + (pb+2)*32 + g] = e2;
                wbTp[L*1024 + (pb+3)*32 + g] = e3;
            }
        } else if (idx < 778) {
            const int c = idx - 768;
            const float4 f = *(const float4*)(w4 + (size_t)c * 256 + 4*lane);
            const u64 e0 = __ballot(f.x >= 0.0f);
            const u64 e1 = __ballot(f.y >= 0.0f);
            const u64 e2 = __ballot(f.z >= 0.0f);
            const u64 e3 = __ballot(f.w >= 0.0f);
            if (lane == 0) {
                w4b[c*4+0] = e0; w4b[c*4+1] = e1; w4b[c*4+2] = e2; w4b[c*4+3] = e3;
            }
        }
    } else {
        for (int i = threadIdx.x; i < 1040; i += 256) { gsum[i] = 0; gsq[i] = 0; }
        if (threadIdx.x < 16) {
            gmin[threadIdx.x] = INT_MAX;
            gmax[threadIdx.x] = INT_MIN;
            colsum[threadIdx.x] = 0.0;
        }
    }
}

// ---------------------------------------------------------------------------
// bn_threshold: exact integer binarization threshold from exact stats.
// ---------------------------------------------------------------------------
__device__ __forceinline__ void bn_threshold(long long sv, long long qv,
    float gaf, float bef, int& sg, int& t)
{
    const double mean = (double)sv / (double)B_ROWS;
    double var = (double)qv / (double)B_ROWS - mean * mean;
    if (var < 0.0) var = 0.0;
    const double rs    = 1.0 / sqrt(var + BN_EPS);
    const double scale = (double)gaf * rs;
    const double bt    = (double)bef;
    if (scale > 0.0) {
        const double tt = fmin(fmax(mean - bt / scale, -1e6), 1e6);
        sg = 1; t = (int)ceil(tt);
    } else if (scale < 0.0) {
        const double tt = fmin(fmax(mean - bt / scale, -1e6), 1e6);
        sg = -1; t = (int)(-floor(tt));
    } else { sg = 0; t = (bt >= 0.0) ? INT_MIN : 1; }
}

// ---------------------------------------------------------------------------
// gemm_coal: 128 rows x 256 cols popcount GEMM (512 thr), coalesced v stores.
// (R7-proven, used by layer0.) ct=tid&31 cols 8ct..+7; rt=tid>>5 rows rt+16j.
// ---------------------------------------------------------------------------
template<int KW>
__device__ __forceinline__ void gemm_coal(const u64* __restrict__ sA,
    const u64* __restrict__ sWp, int K, int row0,
    short* __restrict__ vout, long long* gsumL, long long* gsqL,
    int* sS, int* sQ)
{
    const int tid = threadIdx.x;
    const int ct  = tid & 31;
    const int rt  = tid >> 5;          // 0..15

    unsigned p2[8][4];                 // [row j][colpair e2]
#pragma unroll
    for (int j = 0; j < 8; ++j)
#pragma unroll
        for (int e2 = 0; e2 < 4; ++e2) p2[j][e2] = 0;

#pragma unroll 1
    for (int k = 0; k < KW; ++k) {
        u64 a[8];
#pragma unroll
        for (int j = 0; j < 8; ++j) a[j] = sA[k*128 + rt + 16*j];
        u64 w[8];
#pragma unroll
        for (int e = 0; e < 8; ++e) w[e] = sWp[(e*KW + k)*32 + ct];
#pragma unroll
        for (int j = 0; j < 8; ++j)
#pragma unroll
            for (int e2 = 0; e2 < 4; ++e2)
                p2[j][e2] += (unsigned)__popcll(a[j] ^ w[2*e2])
                           + ((unsigned)__popcll(a[j] ^ w[2*e2+1]) << 16);
    }

    int s8[8], q8[8];
#pragma unroll
    for (int e = 0; e < 8; ++e) { s8[e] = 0; q8[e] = 0; }

#pragma unroll
    for (int j = 0; j < 8; ++j) {
        const int r = row0 + rt + 16*j;
        unsigned pk[4];
#pragma unroll
        for (int e2 = 0; e2 < 4; ++e2) {
            const int v0 = K - 2 * (int)(p2[j][e2] & 0xFFFFu);
            const int v1 = K - 2 * (int)(p2[j][e2] >> 16);
            s8[2*e2]   += v0; q8[2*e2]   += v0*v0;
            s8[2*e2+1] += v1; q8[2*e2+1] += v1*v1;
            pk[e2] = (unsigned)(unsigned short)(short)v0
                   | ((unsigned)(unsigned short)(short)v1 << 16);
        }
        *(uint4*)(vout + (size_t)r * 256 + 8*ct) = make_uint4(pk[0], pk[1], pk[2], pk[3]);
    }

#pragma unroll
    for (int e = 0; e < 8; ++e) {
        s8[e] += __shfl_xor(s8[e], 32);
        q8[e] += __shfl_xor(q8[e], 32);
    }
    if ((tid & 63) < 32) {
#pragma unroll
        for (int e = 0; e < 8; ++e) {
            atomicAdd(&sS[8*ct + e], s8[e]);
            atomicAdd(&sQ[8*ct + e], q8[e]);
        }
    }
    __syncthreads();
    if (tid < 256) {
        atomicAdd((u64*)&gsumL[tid], (u64)(long long)sS[tid]);
        atomicAdd((u64*)&gsqL[tid],  (u64)(long long)sQ[tid]);
    }
}

// ---------------------------------------------------------------------------
// gemm_coal64: 64 rows x 256 cols popcount GEMM (256 thr), coalesced stores.
// ct=tid&31 cols 8ct..+7; rt=tid>>5 (0..7) rows rt+8j (j<8). Same wave-local
// stats fold as gemm_coal (shfl_xor(32) merges lane l / l+32, same ct).
// ~95 live VGPRs -> needs cap >= 128 (launch_bounds(256,4)).
// ---------------------------------------------------------------------------
template<int KW>
__device__ __forceinline__ void gemm_coal64(const u64* __restrict__ sA,
    const u64* __restrict__ sWp, int K, int row0,
    short* __restrict__ vout, long long* gsumL, long long* gsqL,
    int* sS, int* sQ)
{
    const int tid = threadIdx.x;
    const int ct  = tid & 31;
    const int rt  = tid >> 5;          // 0..7

    unsigned p2[8][4];
#pragma unroll
    for (int j = 0; j < 8; ++j)
#pragma unroll
        for (int e2 = 0; e2 < 4; ++e2) p2[j][e2] = 0;

#pragma unroll 1
    for (int k = 0; k < KW; ++k) {
        u64 a[8];
#pragma unroll
        for (int j = 0; j < 8; ++j) a[j] = sA[k*64 + rt + 8*j];
        u64 w[8];
#pragma unroll
        for (int e = 0; e < 8; ++e) w[e] = sWp[(e*KW + k)*32 + ct];
#pragma unroll
        for (int j = 0; j < 8; ++j)
#pragma unroll
            for (int e2 = 0; e2 < 4; ++e2)
                p2[j][e2] += (unsigned)__popcll(a[j] ^ w[2*e2])
                           + ((unsigned)__popcll(a[j] ^ w[2*e2+1]) << 16);
    }

    int s8[8], q8[8];
#pragma unroll
    for (int e = 0; e < 8; ++e) { s8[e] = 0; q8[e] = 0; }

#pragma unroll
    for (int j = 0; j < 8; ++j) {
        const int r = row0 + rt + 8*j;
        unsigned pk[4];
#pragma unroll
        for (int e2 = 0; e2 < 4; ++e2) {
            const int v0 = K - 2 * (int)(p2[j][e2] & 0xFFFFu);
            const int v1 = K - 2 * (int)(p2[j][e2] >> 16);
            s8[2*e2]   += v0; q8[2*e2]   += v0*v0;
            s8[2*e2+1] += v1; q8[2*e2+1] += v1*v1;
            pk[e2] = (unsigned)(unsigned short)(short)v0
                   | ((unsigned)(unsigned short)(short)v1 << 16);
        }
        *(uint4*)(vout + (size_t)r * 256 + 8*ct) = make_uint4(pk[0], pk[1], pk[2], pk[3]);
    }

#pragma unroll
    for (int e = 0; e < 8; ++e) {
        s8[e] += __shfl_xor(s8[e], 32);
        q8[e] += __shfl_xor(q8[e], 32);
    }
    if ((tid & 63) < 32) {
#pragma unroll
        for (int e = 0; e < 8; ++e) {
            atomicAdd(&sS[8*ct + e], s8[e]);
            atomicAdd(&sQ[8*ct + e], q8[e]);
        }
    }
    __syncthreads();
    atomicAdd((u64*)&gsumL[tid], (u64)(long long)sS[tid]);
    atomicAdd((u64*)&gsqL[tid],  (u64)(long long)sQ[tid]);
}

// ---------------------------------------------------------------------------
// layer0_kernel: stage bitsx tile + w0 e-planes, GEMM, stats, coalesced v.
// (R7-proven, unchanged.)
// ---------------------------------------------------------------------------
__global__ __launch_bounds__(512, 4) void layer0_kernel(
    const u64* __restrict__ bitsx, const u64* __restrict__ wb0p,
    short* __restrict__ v, long long* gsum, long long* gsq)
{
    __shared__ __align__(16) u64 sA[13*128];
    __shared__ __align__(16) u64 sWp[13*8*32];
    __shared__ int sS[256], sQ[256];
    const int tid  = threadIdx.x;
    const int row0 = blockIdx.x * 128;
    for (int i = tid; i < 13*128; i += 512)
        sA[i] = bitsx[(size_t)(i >> 7)*65536 + row0 + (i & 127)];
    for (int i = tid; i < 13*8*32; i += 512) sWp[i] = wb0p[i];
    if (tid < 256) { sS[tid] = 0; sQ[tid] = 0; }
    __syncthreads();
    gemm_coal<13>(sA, sWp, 784, row0, v, gsum, gsq, sS, sQ);
}

// ---------------------------------------------------------------------------
// layer_mid_kernel v3: 64-row tiles, 256 threads, 1024 blocks, min-waves 4
// (VGPR cap 128, no spill; 4 blocks/CU for cross-block phase overlap).
// thresholds -> rebinarize v in-LDS -> GEMM -> stats -> v in place.
// ---------------------------------------------------------------------------
__global__ __launch_bounds__(256, 4) void layer_mid_kernel(
    short* v,
    const long long* __restrict__ gsumP, const long long* __restrict__ gsqP,
    const float* __restrict__ gaP, const float* __restrict__ beP,
    const u64* __restrict__ wbTpL, long long* gsumC, long long* gsqC)
{
    __shared__ __align__(16) u64 sA[4*64];
    __shared__ __align__(16) u64 sWp[4*8*32];
    __shared__ int sSgn[256], sThr[256];
    __shared__ int sS[256], sQ[256];
    const int tid  = threadIdx.x;
    const int lane = tid & 63;
    const int wv   = tid >> 6;          // 0..3
    const int row0 = blockIdx.x * 64;

    for (int i = tid; i < 4*8*32; i += 256) sWp[i] = wbTpL[i];
    {
        int sg, t;
        bn_threshold(gsumP[tid], gsqP[tid], gaP[tid], beP[tid], sg, t);
        sSgn[tid] = sg; sThr[tid] = t;
        sS[tid] = 0; sQ[tid] = 0;
    }
    __syncthreads();

    const int4 sg4 = *(const int4*)&sSgn[4*lane];
    const int4 th4 = *(const int4*)&sThr[4*lane];
#pragma unroll 2
    for (int i = 0; i < 16; ++i) {
        const int r = wv * 16 + i;          // 0..63
        const short4 vv = *(const short4*)(v + (size_t)(row0 + r)*256 + 4*lane);
        const u64 e0 = __ballot(sg4.x * (int)vv.x >= th4.x);
        const u64 e1 = __ballot(sg4.y * (int)vv.y >= th4.y);
        const u64 e2 = __ballot(sg4.z * (int)vv.z >= th4.z);
        const u64 e3 = __ballot(sg4.w * (int)vv.w >= th4.w);
        if (lane == 0) {
            sA[0*64 + r] = e0; sA[1*64 + r] = e1;
            sA[2*64 + r] = e2; sA[3*64 + r] = e3;
        }
    }
    __syncthreads();
    gemm_coal64<4>(sA, sWp, 256, row0, v, gsumC, gsqC, sS, sQ);
}

// ---------------------------------------------------------------------------
// layer4_kernel v2 (R7-proven): 512 x 512 = 4096 waves, 16 rows/wave, no LDS
// round-trip: ballots -> lane c<10 popcounts class c -> v4 + exact stats.
// ---------------------------------------------------------------------------
__global__ __launch_bounds__(512) void layer4_kernel(
    const short* __restrict__ v,
    const long long* __restrict__ gsumP, const long long* __restrict__ gsqP,
    const float* __restrict__ gaP, const float* __restrict__ beP,
    const u64* __restrict__ w4b, short* __restrict__ v4,
    long long* gsum4, long long* gsq4, int* gmin, int* gmax)
{
    __shared__ int sSgn[256], sThr[256];
    __shared__ int sS[10], sQ[10], sMn[10], sMx[10];
    const int tid  = threadIdx.x;
    const int lane = tid & 63;
    const int wv   = tid >> 6;          // 0..7

    if (tid < 256) {
        int sg, t;
        bn_threshold(gsumP[tid], gsqP[tid], gaP[tid], beP[tid], sg, t);
        sSgn[tid] = sg; sThr[tid] = t;
    }
    if (tid < 10) { sS[tid] = 0; sQ[tid] = 0; sMn[tid] = INT_MAX; sMx[tid] = INT_MIN; }
    __syncthreads();

    const int4 sg4 = *(const int4*)&sSgn[4*lane];
    const int4 th4 = *(const int4*)&sThr[4*lane];

    u64 wc0 = 0, wc1 = 0, wc2 = 0, wc3 = 0;
    if (lane < 10) {
        wc0 = w4b[lane*4+0]; wc1 = w4b[lane*4+1];
        wc2 = w4b[lane*4+2]; wc3 = w4b[lane*4+3];
    }

    int accS = 0, accQ = 0, mn = INT_MAX, mx = INT_MIN;
    const int waveId = blockIdx.x * 8 + wv;           // 0..4095
    const int r0 = waveId * 16;
#pragma unroll 2
    for (int i = 0; i < 16; ++i) {
        const int r = r0 + i;
        const short4 vv = *(const short4*)(v + (size_t)r*256 + 4*lane);
        const u64 e0 = __ballot(sg4.x * (int)vv.x >= th4.x);
        const u64 e1 = __ballot(sg4.y * (int)vv.y >= th4.y);
        const u64 e2 = __ballot(sg4.z * (int)vv.z >= th4.z);
        const u64 e3 = __ballot(sg4.w * (int)vv.w >= th4.w);
        if (lane < 10) {
            const int p = (int)__popcll(e0 ^ wc0) + (int)__popcll(e1 ^ wc1)
                        + (int)__popcll(e2 ^ wc2) + (int)__popcll(e3 ^ wc3);
            const int vr = 256 - 2*p;
            v4[(size_t)r*10 + lane] = (short)vr;
            accS += vr; accQ += vr*vr;
            mn = min(mn, vr); mx = max(mx, vr);
        }
    }
    if (lane < 10) {
        atomicAdd(&sS[lane], accS);
        atomicAdd(&sQ[lane], accQ);
        atomicMin(&sMn[lane], mn);
        atomicMax(&sMx[lane], mx);
    }
    __syncthreads();
    if (tid < 10) {
        atomicAdd((u64*)&gsum4[tid], (u64)(long long)sS[tid]);
        atomicAdd((u64*)&gsq4[tid],  (u64)(long long)sQ[tid]);
        atomicMin(&gmin[tid], sMn[tid]);
        atomicMax(&gmax[tid], sMx[tid]);
    }
}

// ---------------------------------------------------------------------------
// colsum_kernel: zs/zb (exact from integer min/max) + partial exp-sums.
// ---------------------------------------------------------------------------
__global__ __launch_bounds__(256) void colsum_kernel(
    const short* __restrict__ v4,
    const long long* __restrict__ gsum4, const long long* __restrict__ gsq4,
    const int* __restrict__ gmin, const int* __restrict__ gmax,
    const float* __restrict__ g4, const float* __restrict__ b4,
    double* zsg, double* zbg, double* colsum)
{
    __shared__ double sred[256];
    __shared__ double sZ[2];
    const int c     = blockIdx.x % 10;
    const int chunk = blockIdx.x / 10;
    const int tid   = threadIdx.x;
    if (tid == 0) {
        const double mean = (double)gsum4[c] / (double)B_ROWS;
        double var = (double)gsq4[c] / (double)B_ROWS - mean * mean;
        if (var < 0.0) var = 0.0;
        const double rs    = 1.0 / sqrt(var + BN_EPS);
        const double scale = (double)g4[c] * rs;
        const double bias  = (double)b4[c] - mean * scale;
        const double z1 = scale * (double)gmin[c] + bias;
        const double z2 = scale * (double)gmax[c] + bias;
        const double zb = bias - fmax(z1, z2);
        sZ[0] = scale; sZ[1] = zb;
        zsg[c] = scale; zbg[c] = zb;       // redundant identical writes, benign
    }
    __syncthreads();
    const double zs = sZ[0], zb = sZ[1];
    double acc = 0.0;
    const int r0 = chunk * 1024;
#pragma unroll
    for (int j = 0; j < 4; ++j) {
        const int r = r0 + j*256 + tid;
        acc += (double)expf((float)(zs * (double)v4[(size_t)r*10 + c] + zb));
    }
    sred[tid] = acc; __syncthreads();
    for (int s = 128; s > 0; s >>= 1) {
        if (tid < s) sred[tid] += sred[tid + s];
        __syncthreads();
    }
    if (tid == 0) atomicAdd(&colsum[c], sred[0]);
}

// ---------------------------------------------------------------------------
// out_kernel: out = expf(zs*v + zb) / colsum, coalesced.
// ---------------------------------------------------------------------------
__global__ __launch_bounds__(256) void out_kernel(
    const short* __restrict__ v4, const double* __restrict__ zsg,
    const double* __restrict__ zbg, const double* __restrict__ colsum,
    float* __restrict__ out)
{
    const int idx = blockIdx.x * 256 + threadIdx.x;
    if (idx >= B_ROWS * 10) return;
    const int c = idx % 10;
    const float e = expf((float)(zsg[c] * (double)v4[idx] + zbg[c]));
    out[idx] = (float)((double)e / colsum[c]);
}

// ---------------------------------------------------------------------------
extern "C" void kernel_launch(void* const* d_in, const int* in_sizes, int n_in,
                              void* d_out, int out_size, void* d_ws, size_t ws_size,
                              hipStream_t stream)
{
    const float* x  = (const float*)d_in[0];
    const float* w0 = (const float*)d_in[1];
    const float* g0 = (const float*)d_in[2];
    const float* b0 = (const float*)d_in[3];
    const float* w1 = (const float*)d_in[4];
    const float* g1 = (const float*)d_in[5];
    const float* b1 = (const float*)d_in[6];
    const float* w2 = (const float*)d_in[7];
    const float* g2 = (const float*)d_in[8];
    const float* b2 = (const float*)d_in[9];
    const float* w3 = (const float*)d_in[10];
    const float* g3 = (const float*)d_in[11];
    const float* b3 = (const float*)d_in[12];
    const float* w4 = (const float*)d_in[13];
    const float* g4 = (const float*)d_in[14];
    const float* b4 = (const float*)d_in[15];

    char* p = (char*)d_ws;
    auto alloc = [&](size_t bytes) -> char* {
        char* r = p;
        p += (bytes + 255) & ~(size_t)255;
        return r;
    };
    u64*       bitsx  = (u64*)alloc(13ull*65536*8);
    u64*       wb0p   = (u64*)alloc(13*8*32*8);
    u64*       wbTp   = (u64*)alloc(3*1024*8);
    u64*       w4b    = (u64*)alloc(40*8);
    short*     v      = (short*)alloc(65536ull*256*2);
    short*     v4     = (short*)alloc(65536ull*10*2);
    long long* gsum   = (long long*)alloc(1040*8);
    long long* gsq    = (long long*)alloc(1040*8);
    int*       gmin   = (int*)alloc(16*4);
    int*       gmax   = (int*)alloc(16*4);
    double*    colsum = (double*)alloc(16*8);
    double*    zsg    = (double*)alloc(16*8);
    double*    zbg    = (double*)alloc(16*8);
    float*     out    = (float*)d_out;

    long long* gsum4 = gsum + 1024;
    long long* gsq4  = gsq  + 1024;

    prep_all<<<2308, 256, 0, stream>>>(x, w0, w1, w2, w3, w4,
                                       bitsx, wb0p, wbTp, w4b,
                                       gsum, gsq, gmin, gmax, colsum);

    layer0_kernel<<<512, 512, 0, stream>>>(bitsx, wb0p, v, gsum, gsq);

    layer_mid_kernel<<<1024, 256, 0, stream>>>(v, gsum, gsq, g0, b0,
                                               wbTp + 0*1024, gsum + 256, gsq + 256);
    layer_mid_kernel<<<1024, 256, 0, stream>>>(v, gsum + 256, gsq + 256, g1, b1,
                                               wbTp + 1*1024, gsum + 512, gsq + 512);
    layer_mid_kernel<<<1024, 256, 0, stream>>>(v, gsum + 512, gsq + 512, g2, b2,
                                               wbTp + 2*1024, gsum + 768, gsq + 768);

    layer4_kernel<<<512, 512, 0, stream>>>(v, gsum + 768, gsq + 768, g3, b3,
                                           w4b, v4, gsum4, gsq4, gmin, gmax);

    colsum_kernel<<<640, 256, 0, stream>>>(v4, gsum4, gsq4, gmin, gmax, g4, b4,
                                           zsg, zbg, colsum);

    out_kernel<<<2560, 256, 0, stream>>>(v4, zsg, zbg, colsum, out);
}

// Round 14
// 197.737 us; speedup vs baseline: 1.4345x; 1.1398x over previous
//
#include <hip/hip_runtime.h>
#include <cstdint>
#include <climits>
#include <cstddef>

typedef unsigned long long u64;

#define B_ROWS 65536
#define BN_EPS 1e-5

// ---------------------------------------------------------------------------
// R11-proven structure (202.7us, absmax=0, best of 13 rounds). Change vs R11:
// x-pack TLP doubled (4096 blocks x 4 waves x 4 rows/wave, was 8 rows/wave)
// to shorten the per-wave dependent load->ballot chain. Mids reverted to
// R11's 128-row/512-thr config (R12/R13 small-tile experiments falsified).
// Layouts (float4-interleaved, verified absmax=0 rounds 3-13):
//   x/layer0 A: 13 words/row. word k=4*cg+e (cg<3): bit l <-> col cg*256+4l+e.
//               word 12: cols 768..783 as 4 nibbles.
//   layers 1..4 A: 4 words, word e: bit l <-> col 4l+e.
//   Weights in E-PLANE layout: wbXp[((c&7)*KW + k)*32 + (c>>3)].
//   w4b[c*4+e] interleaved words (broadcast reads).
//   bitsx col-major [word][row]; v int16 [row][256] (uint4 stores);
//   v4 int16 [row][10].
// ---------------------------------------------------------------------------

// ---------------------------------------------------------------------------
// prep_all: pack x (blocks 0..4095, 4 rows/wave), w0 (4096..4159),
// w1..w4 (4160..4354), zero stats (4355). Mostly HBM-bound on x.
// ---------------------------------------------------------------------------
__global__ __launch_bounds__(256) void prep_all(
    const float* __restrict__ x, const float* __restrict__ w0,
    const float* __restrict__ w1, const float* __restrict__ w2,
    const float* __restrict__ w3, const float* __restrict__ w4,
    u64* __restrict__ bitsx, u64* __restrict__ wb0p, u64* __restrict__ wbTp,
    u64* __restrict__ w4b,
    long long* gsum, long long* gsq, int* gmin, int* gmax, double* colsum)
{
    const int lane = threadIdx.x & 63;
    const int wv   = threadIdx.x >> 6;
    const int b    = blockIdx.x;

    if (b < 4096) {
        // ---- x pack: wave per 4 rows (16384 waves total) ----
        const int gw = b * 4 + wv;
#pragma unroll
        for (int i = 0; i < 4; ++i) {
            const int row = gw * 4 + i;
            const float4* xr = (const float4*)(x + (size_t)row * 784);
#pragma unroll
            for (int cg = 0; cg < 3; ++cg) {
                const float4 f = xr[cg*64 + lane];
                const u64 e0 = __ballot(f.x >= 0.5f);
                const u64 e1 = __ballot(f.y >= 0.5f);
                const u64 e2 = __ballot(f.z >= 0.5f);
                const u64 e3 = __ballot(f.w >= 0.5f);
                if (lane == 0) {
                    bitsx[(size_t)(cg*4+0)*65536 + row] = e0;
                    bitsx[(size_t)(cg*4+1)*65536 + row] = e1;
                    bitsx[(size_t)(cg*4+2)*65536 + row] = e2;
                    bitsx[(size_t)(cg*4+3)*65536 + row] = e3;
                }
            }
            float4 f = make_float4(-1.f, -1.f, -1.f, -1.f);
            if (lane < 4) f = xr[192 + lane];
            const u64 e0 = __ballot(f.x >= 0.5f) & 0xF;
            const u64 e1 = __ballot(f.y >= 0.5f) & 0xF;
            const u64 e2 = __ballot(f.z >= 0.5f) & 0xF;
            const u64 e3 = __ballot(f.w >= 0.5f) & 0xF;
            if (lane == 0)
                bitsx[(size_t)12*65536 + row] = e0 | (e1 << 4) | (e2 << 8) | (e3 << 12);
        }
    } else if (b < 4160) {
        // ---- w0 pack -> e-plane layout ----
        const int c = (b - 4096) * 4 + wv;
        const int pb = (c & 7) * 13;      // plane base
        const int g  = c >> 3;            // col group
        const float4* row = (const float4*)(w0 + (size_t)c * 784);
#pragma unroll
        for (int cg = 0; cg < 3; ++cg) {
            const float4 f = row[cg*64 + lane];
            const u64 e0 = __ballot(f.x >= 0.0f);
            const u64 e1 = __ballot(f.y >= 0.0f);
            const u64 e2 = __ballot(f.z >= 0.0f);
            const u64 e3 = __ballot(f.w >= 0.0f);
            if (lane == 0) {
                wb0p[(pb + cg*4+0)*32 + g] = e0;
                wb0p[(pb + cg*4+1)*32 + g] = e1;
                wb0p[(pb + cg*4+2)*32 + g] = e2;
                wb0p[(pb + cg*4+3)*32 + g] = e3;
            }
        }
        float4 f = make_float4(-1.f, -1.f, -1.f, -1.f);
        if (lane < 4) f = row[192 + lane];
        const u64 e0 = __ballot(f.x >= 0.0f) & 0xF;
        const u64 e1 = __ballot(f.y >= 0.0f) & 0xF;
        const u64 e2 = __ballot(f.z >= 0.0f) & 0xF;
        const u64 e3 = __ballot(f.w >= 0.0f) & 0xF;
        if (lane == 0) wb0p[(pb + 12)*32 + g] = e0 | (e1 << 4) | (e2 << 8) | (e3 << 12);
    } else if (b < 4355) {
        // ---- w1..w3 -> e-plane; w4 -> w4b[c*4+e] ----
        const int idx = (b - 4160) * 4 + wv;         // 0..779
        if (idx < 768) {
            const int L = idx >> 8, c = idx & 255;
            const float* ws = (L == 0) ? w1 : (L == 1) ? w2 : w3;
            const float4 f = *(const float4*)(ws + (size_t)c * 256 + 4*lane);
            const u64 e0 = __ballot(f.x >= 0.0f);
            const u64 e1 = __ballot(f.y >= 0.0f);
            const u64 e2 = __ballot(f.z >= 0.0f);
            const u64 e3 = __ballot(f.w >= 0.0f);
            if (lane == 0) {
                const int pb = (c & 7) * 4;
                const int g  = c >> 3;
                wbTp[L*1024 + (pb+0)*32 + g] = e0;
                wbTp[L*1024 + (pb+1)*32 + g] = e1;
                wbTp[L*1024 + (pb+2)*32 + g] = e2;
                wbTp[L*1024 + (pb+3)*32 + g] = e3;
            }
        } else if (idx < 778) {
            const int c = idx - 768;
            const float4 f = *(const float4*)(w4 + (size_t)c * 256 + 4*lane);
            const u64 e0 = __ballot(f.x >= 0.0f);
            const u64 e1 = __ballot(f.y >= 0.0f);
            const u64 e2 = __ballot(f.z >= 0.0f);
            const u64 e3 = __ballot(f.w >= 0.0f);
            if (lane == 0) {
                w4b[c*4+0] = e0; w4b[c*4+1] = e1; w4b[c*4+2] = e2; w4b[c*4+3] = e3;
            }
        }
    } else {
        for (int i = threadIdx.x; i < 1040; i += 256) { gsum[i] = 0; gsq[i] = 0; }
        if (threadIdx.x < 16) {
            gmin[threadIdx.x] = INT_MAX;
            gmax[threadIdx.x] = INT_MIN;
            colsum[threadIdx.x] = 0.0;
        }
    }
}

// ---------------------------------------------------------------------------
// bn_threshold: exact integer binarization threshold from exact stats.
// ---------------------------------------------------------------------------
__device__ __forceinline__ void bn_threshold(long long sv, long long qv,
    float gaf, float bef, int& sg, int& t)
{
    const double mean = (double)sv / (double)B_ROWS;
    double var = (double)qv / (double)B_ROWS - mean * mean;
    if (var < 0.0) var = 0.0;
    const double rs    = 1.0 / sqrt(var + BN_EPS);
    const double scale = (double)gaf * rs;
    const double bt    = (double)bef;
    if (scale > 0.0) {
        const double tt = fmin(fmax(mean - bt / scale, -1e6), 1e6);
        sg = 1; t = (int)ceil(tt);
    } else if (scale < 0.0) {
        const double tt = fmin(fmax(mean - bt / scale, -1e6), 1e6);
        sg = -1; t = (int)(-floor(tt));
    } else { sg = 0; t = (bt >= 0.0) ? INT_MIN : 1; }
}

// ---------------------------------------------------------------------------
// gemm_coal: 128 rows x 256 cols popcount GEMM (512 thr), coalesced v stores.
// (R7/R11-proven.) ct=tid&31 cols 8ct..+7; rt=tid>>5 rows rt+16j.
// ---------------------------------------------------------------------------
template<int KW>
__device__ __forceinline__ void gemm_coal(const u64* __restrict__ sA,
    const u64* __restrict__ sWp, int K, int row0,
    short* __restrict__ vout, long long* gsumL, long long* gsqL,
    int* sS, int* sQ)
{
    const int tid = threadIdx.x;
    const int ct  = tid & 31;
    const int rt  = tid >> 5;          // 0..15

    unsigned p2[8][4];                 // [row j][colpair e2]
#pragma unroll
    for (int j = 0; j < 8; ++j)
#pragma unroll
        for (int e2 = 0; e2 < 4; ++e2) p2[j][e2] = 0;

#pragma unroll 1
    for (int k = 0; k < KW; ++k) {
        u64 a[8];
#pragma unroll
        for (int j = 0; j < 8; ++j) a[j] = sA[k*128 + rt + 16*j];
        u64 w[8];
#pragma unroll
        for (int e = 0; e < 8; ++e) w[e] = sWp[(e*KW + k)*32 + ct];
#pragma unroll
        for (int j = 0; j < 8; ++j)
#pragma unroll
            for (int e2 = 0; e2 < 4; ++e2)
                p2[j][e2] += (unsigned)__popcll(a[j] ^ w[2*e2])
                           + ((unsigned)__popcll(a[j] ^ w[2*e2+1]) << 16);
    }

    int s8[8], q8[8];
#pragma unroll
    for (int e = 0; e < 8; ++e) { s8[e] = 0; q8[e] = 0; }

#pragma unroll
    for (int j = 0; j < 8; ++j) {
        const int r = row0 + rt + 16*j;
        unsigned pk[4];
#pragma unroll
        for (int e2 = 0; e2 < 4; ++e2) {
            const int v0 = K - 2 * (int)(p2[j][e2] & 0xFFFFu);
            const int v1 = K - 2 * (int)(p2[j][e2] >> 16);
            s8[2*e2]   += v0; q8[2*e2]   += v0*v0;
            s8[2*e2+1] += v1; q8[2*e2+1] += v1*v1;
            pk[e2] = (unsigned)(unsigned short)(short)v0
                   | ((unsigned)(unsigned short)(short)v1 << 16);
        }
        *(uint4*)(vout + (size_t)r * 256 + 8*ct) = make_uint4(pk[0], pk[1], pk[2], pk[3]);
    }

#pragma unroll
    for (int e = 0; e < 8; ++e) {
        s8[e] += __shfl_xor(s8[e], 32);
        q8[e] += __shfl_xor(q8[e], 32);
    }
    if ((tid & 63) < 32) {
#pragma unroll
        for (int e = 0; e < 8; ++e) {
            atomicAdd(&sS[8*ct + e], s8[e]);
            atomicAdd(&sQ[8*ct + e], q8[e]);
        }
    }
    __syncthreads();
    if (tid < 256) {
        atomicAdd((u64*)&gsumL[tid], (u64)(long long)sS[tid]);
        atomicAdd((u64*)&gsqL[tid],  (u64)(long long)sQ[tid]);
    }
}

// ---------------------------------------------------------------------------
// layer0_kernel: stage bitsx tile + w0 e-planes, GEMM, stats, coalesced v.
// (R7/R11-proven, unchanged.)
// ---------------------------------------------------------------------------
__global__ __launch_bounds__(512, 4) void layer0_kernel(
    const u64* __restrict__ bitsx, const u64* __restrict__ wb0p,
    short* __restrict__ v, long long* gsum, long long* gsq)
{
    __shared__ __align__(16) u64 sA[13*128];
    __shared__ __align__(16) u64 sWp[13*8*32];
    __shared__ int sS[256], sQ[256];
    const int tid  = threadIdx.x;
    const int row0 = blockIdx.x * 128;
    for (int i = tid; i < 13*128; i += 512)
        sA[i] = bitsx[(size_t)(i >> 7)*65536 + row0 + (i & 127)];
    for (int i = tid; i < 13*8*32; i += 512) sWp[i] = wb0p[i];
    if (tid < 256) { sS[tid] = 0; sQ[tid] = 0; }
    __syncthreads();
    gemm_coal<13>(sA, sWp, 784, row0, v, gsum, gsq, sS, sQ);
}

// ---------------------------------------------------------------------------
// layer_mid_kernel (R11-proven config): 128 rows, 512 thr, 512 blocks.
// thresholds (redundant/block, exact) -> rebinarize v in-LDS -> GEMM ->
// stats -> v in place.
// ---------------------------------------------------------------------------
__global__ __launch_bounds__(512, 4) void layer_mid_kernel(
    short* v,
    const long long* __restrict__ gsumP, const long long* __restrict__ gsqP,
    const float* __restrict__ gaP, const float* __restrict__ beP,
    const u64* __restrict__ wbTpL, long long* gsumC, long long* gsqC)
{
    __shared__ __align__(16) u64 sA[4*128];
    __shared__ __align__(16) u64 sWp[4*8*32];
    __shared__ int sSgn[256], sThr[256];
    __shared__ int sS[256], sQ[256];
    const int tid  = threadIdx.x;
    const int lane = tid & 63;
    const int wv   = tid >> 6;
    const int row0 = blockIdx.x * 128;

    for (int i = tid; i < 4*8*32; i += 512) sWp[i] = wbTpL[i];
    if (tid < 256) {
        int sg, t;
        bn_threshold(gsumP[tid], gsqP[tid], gaP[tid], beP[tid], sg, t);
        sSgn[tid] = sg; sThr[tid] = t;
        sS[tid] = 0; sQ[tid] = 0;
    }
    __syncthreads();

    const int4 sg4 = *(const int4*)&sSgn[4*lane];
    const int4 th4 = *(const int4*)&sThr[4*lane];
    for (int i = 0; i < 16; ++i) {
        const int r = wv * 16 + i;
        const short4 vv = *(const short4*)(v + (size_t)(row0 + r)*256 + 4*lane);
        const u64 e0 = __ballot(sg4.x * (int)vv.x >= th4.x);
        const u64 e1 = __ballot(sg4.y * (int)vv.y >= th4.y);
        const u64 e2 = __ballot(sg4.z * (int)vv.z >= th4.z);
        const u64 e3 = __ballot(sg4.w * (int)vv.w >= th4.w);
        if (lane == 0) {
            sA[0*128 + r] = e0; sA[1*128 + r] = e1;
            sA[2*128 + r] = e2; sA[3*128 + r] = e3;
        }
    }
    __syncthreads();
    gemm_coal<4>(sA, sWp, 256, row0, v, gsumC, gsqC, sS, sQ);
}

// ---------------------------------------------------------------------------
// layer4_kernel v2 (R7/R11-proven): 512 x 512 = 4096 waves, 16 rows/wave, no
// LDS round-trip: ballots -> lane c<10 popcounts class c -> v4 + exact stats.
// ---------------------------------------------------------------------------
__global__ __launch_bounds__(512) void layer4_kernel(
    const short* __restrict__ v,
    const long long* __restrict__ gsumP, const long long* __restrict__ gsqP,
    const float* __restrict__ gaP, const float* __restrict__ beP,
    const u64* __restrict__ w4b, short* __restrict__ v4,
    long long* gsum4, long long* gsq4, int* gmin, int* gmax)
{
    __shared__ int sSgn[256], sThr[256];
    __shared__ int sS[10], sQ[10], sMn[10], sMx[10];
    const int tid  = threadIdx.x;
    const int lane = tid & 63;
    const int wv   = tid >> 6;          // 0..7

    if (tid < 256) {
        int sg, t;
        bn_threshold(gsumP[tid], gsqP[tid], gaP[tid], beP[tid], sg, t);
        sSgn[tid] = sg; sThr[tid] = t;
    }
    if (tid < 10) { sS[tid] = 0; sQ[tid] = 0; sMn[tid] = INT_MAX; sMx[tid] = INT_MIN; }
    __syncthreads();

    const int4 sg4 = *(const int4*)&sSgn[4*lane];
    const int4 th4 = *(const int4*)&sThr[4*lane];

    u64 wc0 = 0, wc1 = 0, wc2 = 0, wc3 = 0;
    if (lane < 10) {
        wc0 = w4b[lane*4+0]; wc1 = w4b[lane*4+1];
        wc2 = w4b[lane*4+2]; wc3 = w4b[lane*4+3];
    }

    int accS = 0, accQ = 0, mn = INT_MAX, mx = INT_MIN;
    const int waveId = blockIdx.x * 8 + wv;           // 0..4095
    const int r0 = waveId * 16;
#pragma unroll 2
    for (int i = 0; i < 16; ++i) {
        const int r = r0 + i;
        const short4 vv = *(const short4*)(v + (size_t)r*256 + 4*lane);
        const u64 e0 = __ballot(sg4.x * (int)vv.x >= th4.x);
        const u64 e1 = __ballot(sg4.y * (int)vv.y >= th4.y);
        const u64 e2 = __ballot(sg4.z * (int)vv.z >= th4.z);
        const u64 e3 = __ballot(sg4.w * (int)vv.w >= th4.w);
        if (lane < 10) {
            const int p = (int)__popcll(e0 ^ wc0) + (int)__popcll(e1 ^ wc1)
                        + (int)__popcll(e2 ^ wc2) + (int)__popcll(e3 ^ wc3);
            const int vr = 256 - 2*p;
            v4[(size_t)r*10 + lane] = (short)vr;
            accS += vr; accQ += vr*vr;
            mn = min(mn, vr); mx = max(mx, vr);
        }
    }
    if (lane < 10) {
        atomicAdd(&sS[lane], accS);
        atomicAdd(&sQ[lane], accQ);
        atomicMin(&sMn[lane], mn);
        atomicMax(&sMx[lane], mx);
    }
    __syncthreads();
    if (tid < 10) {
        atomicAdd((u64*)&gsum4[tid], (u64)(long long)sS[tid]);
        atomicAdd((u64*)&gsq4[tid],  (u64)(long long)sQ[tid]);
        atomicMin(&gmin[tid], sMn[tid]);
        atomicMax(&gmax[tid], sMx[tid]);
    }
}

// ---------------------------------------------------------------------------
// colsum_kernel: zs/zb (exact from integer min/max) + partial exp-sums.
// ---------------------------------------------------------------------------
__global__ __launch_bounds__(256) void colsum_kernel(
    const short* __restrict__ v4,
    const long long* __restrict__ gsum4, const long long* __restrict__ gsq4,
    const int* __restrict__ gmin, const int* __restrict__ gmax,
    const float* __restrict__ g4, const float* __restrict__ b4,
    double* zsg, double* zbg, double* colsum)
{
    __shared__ double sred[256];
    __shared__ double sZ[2];
    const int c     = blockIdx.x % 10;
    const int chunk = blockIdx.x / 10;
    const int tid   = threadIdx.x;
    if (tid == 0) {
        const double mean = (double)gsum4[c] / (double)B_ROWS;
        double var = (double)gsq4[c] / (double)B_ROWS - mean * mean;
        if (var < 0.0) var = 0.0;
        const double rs    = 1.0 / sqrt(var + BN_EPS);
        const double scale = (double)g4[c] * rs;
        const double bias  = (double)b4[c] - mean * scale;
        const double z1 = scale * (double)gmin[c] + bias;
        const double z2 = scale * (double)gmax[c] + bias;
        const double zb = bias - fmax(z1, z2);
        sZ[0] = scale; sZ[1] = zb;
        zsg[c] = scale; zbg[c] = zb;       // redundant identical writes, benign
    }
    __syncthreads();
    const double zs = sZ[0], zb = sZ[1];
    double acc = 0.0;
    const int r0 = chunk * 1024;
#pragma unroll
    for (int j = 0; j < 4; ++j) {
        const int r = r0 + j*256 + tid;
        acc += (double)expf((float)(zs * (double)v4[(size_t)r*10 + c] + zb));
    }
    sred[tid] = acc; __syncthreads();
    for (int s = 128; s > 0; s >>= 1) {
        if (tid < s) sred[tid] += sred[tid + s];
        __syncthreads();
    }
    if (tid == 0) atomicAdd(&colsum[c], sred[0]);
}

// ---------------------------------------------------------------------------
// out_kernel: out = expf(zs*v + zb) / colsum, coalesced.
// ---------------------------------------------------------------------------
__global__ __launch_bounds__(256) void out_kernel(
    const short* __restrict__ v4, const double* __restrict__ zsg,
    const double* __restrict__ zbg, const double* __restrict__ colsum,
    float* __restrict__ out)
{
    const int idx = blockIdx.x * 256 + threadIdx.x;
    if (idx >= B_ROWS * 10) return;
    const int c = idx % 10;
    const float e = expf((float)(zsg[c] * (double)v4[idx] + zbg[c]));
    out[idx] = (float)((double)e / colsum[c]);
}

// ---------------------------------------------------------------------------
extern "C" void kernel_launch(void* const* d_in, const int* in_sizes, int n_in,
                              void* d_out, int out_size, void* d_ws, size_t ws_size,
                              hipStream_t stream)
{
    const float* x  = (const float*)d_in[0];
    const float* w0 = (const float*)d_in[1];
    const float* g0 = (const float*)d_in[2];
    const float* b0 = (const float*)d_in[3];
    const float* w1 = (const float*)d_in[4];
    const float* g1 = (const float*)d_in[5];
    const float* b1 = (const float*)d_in[6];
    const float* w2 = (const float*)d_in[7];
    const float* g2 = (const float*)d_in[8];
    const float* b2 = (const float*)d_in[9];
    const float* w3 = (const float*)d_in[10];
    const float* g3 = (const float*)d_in[11];
    const float* b3 = (const float*)d_in[12];
    const float* w4 = (const float*)d_in[13];
    const float* g4 = (const float*)d_in[14];
    const float* b4 = (const float*)d_in[15];

    char* p = (char*)d_ws;
    auto alloc = [&](size_t bytes) -> char* {
        char* r = p;
        p += (bytes + 255) & ~(size_t)255;
        return r;
    };
    u64*       bitsx  = (u64*)alloc(13ull*65536*8);
    u64*       wb0p   = (u64*)alloc(13*8*32*8);
    u64*       wbTp   = (u64*)alloc(3*1024*8);
    u64*       w4b    = (u64*)alloc(40*8);
    short*     v      = (short*)alloc(65536ull*256*2);
    short*     v4     = (short*)alloc(65536ull*10*2);
    long long* gsum   = (long long*)alloc(1040*8);
    long long* gsq    = (long long*)alloc(1040*8);
    int*       gmin   = (int*)alloc(16*4);
    int*       gmax   = (int*)alloc(16*4);
    double*    colsum = (double*)alloc(16*8);
    double*    zsg    = (double*)alloc(16*8);
    double*    zbg    = (double*)alloc(16*8);
    float*     out    = (float*)d_out;

    long long* gsum4 = gsum + 1024;
    long long* gsq4  = gsq  + 1024;

    prep_all<<<4356, 256, 0, stream>>>(x, w0, w1, w2, w3, w4,
                                       bitsx, wb0p, wbTp, w4b,
                                       gsum, gsq, gmin, gmax, colsum);

    layer0_kernel<<<512, 512, 0, stream>>>(bitsx, wb0p, v, gsum, gsq);

    layer_mid_kernel<<<512, 512, 0, stream>>>(v, gsum, gsq, g0, b0,
                                              wbTp + 0*1024, gsum + 256, gsq + 256);
    layer_mid_kernel<<<512, 512, 0, stream>>>(v, gsum + 256, gsq + 256, g1, b1,
                                              wbTp + 1*1024, gsum + 512, gsq + 512);
    layer_mid_kernel<<<512, 512, 0, stream>>>(v, gsum + 512, gsq + 512, g2, b2,
                                              wbTp + 2*1024, gsum + 768, gsq + 768);

    layer4_kernel<<<512, 512, 0, stream>>>(v, gsum + 768, gsq + 768, g3, b3,
                                           w4b, v4, gsum4, gsq4, gmin, gmax);

    colsum_kernel<<<640, 256, 0, stream>>>(v4, gsum4, gsq4, gmin, gmax, g4, b4,
                                           zsg, zbg, colsum);

    out_kernel<<<2560, 256, 0, stream>>>(v4, zsg, zbg, colsum, out);
}

// Round 15
// 196.907 us; speedup vs baseline: 1.4405x; 1.0042x over previous
//
#include <hip/hip_runtime.h>
#include <cstdint>
#include <climits>
#include <cstddef>

typedef unsigned long long u64;

#define B_ROWS 65536
#define BN_EPS 1e-5

// ---------------------------------------------------------------------------
// R14-proven structure (197.7us, absmax=0, best of 14 rounds). Change vs R14:
// x-pack TLP doubled again (8192 blocks x 4 waves x 2 rows/wave, was 4).
// Everything else byte-identical to R14.
// Layouts (float4-interleaved, verified absmax=0 rounds 3-14):
//   x/layer0 A: 13 words/row. word k=4*cg+e (cg<3): bit l <-> col cg*256+4l+e.
//               word 12: cols 768..783 as 4 nibbles.
//   layers 1..4 A: 4 words, word e: bit l <-> col 4l+e.
//   Weights in E-PLANE layout: wbXp[((c&7)*KW + k)*32 + (c>>3)].
//   w4b[c*4+e] interleaved words (broadcast reads).
//   bitsx col-major [word][row]; v int16 [row][256] (uint4 stores);
//   v4 int16 [row][10].
// ---------------------------------------------------------------------------

// ---------------------------------------------------------------------------
// prep_all: pack x (blocks 0..8191, 2 rows/wave), w0 (8192..8255),
// w1..w4 (8256..8450), zero stats (8451). Mostly HBM-bound on x.
// ---------------------------------------------------------------------------
__global__ __launch_bounds__(256) void prep_all(
    const float* __restrict__ x, const float* __restrict__ w0,
    const float* __restrict__ w1, const float* __restrict__ w2,
    const float* __restrict__ w3, const float* __restrict__ w4,
    u64* __restrict__ bitsx, u64* __restrict__ wb0p, u64* __restrict__ wbTp,
    u64* __restrict__ w4b,
    long long* gsum, long long* gsq, int* gmin, int* gmax, double* colsum)
{
    const int lane = threadIdx.x & 63;
    const int wv   = threadIdx.x >> 6;
    const int b    = blockIdx.x;

    if (b < 8192) {
        // ---- x pack: wave per 2 rows (32768 waves total) ----
        const int gw = b * 4 + wv;
#pragma unroll
        for (int i = 0; i < 2; ++i) {
            const int row = gw * 2 + i;
            const float4* xr = (const float4*)(x + (size_t)row * 784);
#pragma unroll
            for (int cg = 0; cg < 3; ++cg) {
                const float4 f = xr[cg*64 + lane];
                const u64 e0 = __ballot(f.x >= 0.5f);
                const u64 e1 = __ballot(f.y >= 0.5f);
                const u64 e2 = __ballot(f.z >= 0.5f);
                const u64 e3 = __ballot(f.w >= 0.5f);
                if (lane == 0) {
                    bitsx[(size_t)(cg*4+0)*65536 + row] = e0;
                    bitsx[(size_t)(cg*4+1)*65536 + row] = e1;
                    bitsx[(size_t)(cg*4+2)*65536 + row] = e2;
                    bitsx[(size_t)(cg*4+3)*65536 + row] = e3;
                }
            }
            float4 f = make_float4(-1.f, -1.f, -1.f, -1.f);
            if (lane < 4) f = xr[192 + lane];
            const u64 e0 = __ballot(f.x >= 0.5f) & 0xF;
            const u64 e1 = __ballot(f.y >= 0.5f) & 0xF;
            const u64 e2 = __ballot(f.z >= 0.5f) & 0xF;
            const u64 e3 = __ballot(f.w >= 0.5f) & 0xF;
            if (lane == 0)
                bitsx[(size_t)12*65536 + row] = e0 | (e1 << 4) | (e2 << 8) | (e3 << 12);
        }
    } else if (b < 8256) {
        // ---- w0 pack -> e-plane layout ----
        const int c = (b - 8192) * 4 + wv;
        const int pb = (c & 7) * 13;      // plane base
        const int g  = c >> 3;            // col group
        const float4* row = (const float4*)(w0 + (size_t)c * 784);
#pragma unroll
        for (int cg = 0; cg < 3; ++cg) {
            const float4 f = row[cg*64 + lane];
            const u64 e0 = __ballot(f.x >= 0.0f);
            const u64 e1 = __ballot(f.y >= 0.0f);
            const u64 e2 = __ballot(f.z >= 0.0f);
            const u64 e3 = __ballot(f.w >= 0.0f);
            if (lane == 0) {
                wb0p[(pb + cg*4+0)*32 + g] = e0;
                wb0p[(pb + cg*4+1)*32 + g] = e1;
                wb0p[(pb + cg*4+2)*32 + g] = e2;
                wb0p[(pb + cg*4+3)*32 + g] = e3;
            }
        }
        float4 f = make_float4(-1.f, -1.f, -1.f, -1.f);
        if (lane < 4) f = row[192 + lane];
        const u64 e0 = __ballot(f.x >= 0.0f) & 0xF;
        const u64 e1 = __ballot(f.y >= 0.0f) & 0xF;
        const u64 e2 = __ballot(f.z >= 0.0f) & 0xF;
        const u64 e3 = __ballot(f.w >= 0.0f) & 0xF;
        if (lane == 0) wb0p[(pb + 12)*32 + g] = e0 | (e1 << 4) | (e2 << 8) | (e3 << 12);
    } else if (b < 8451) {
        // ---- w1..w3 -> e-plane; w4 -> w4b[c*4+e] ----
        const int idx = (b - 8256) * 4 + wv;         // 0..779
        if (idx < 768) {
            const int L = idx >> 8, c = idx & 255;
            const float* ws = (L == 0) ? w1 : (L == 1) ? w2 : w3;
            const float4 f = *(const float4*)(ws + (size_t)c * 256 + 4*lane);
            const u64 e0 = __ballot(f.x >= 0.0f);
            const u64 e1 = __ballot(f.y >= 0.0f);
            const u64 e2 = __ballot(f.z >= 0.0f);
            const u64 e3 = __ballot(f.w >= 0.0f);
            if (lane == 0) {
                const int pb = (c & 7) * 4;
                const int g  = c >> 3;
                wbTp[L*1024 + (pb+0)*32 + g] = e0;
                wbTp[L*1024 + (pb+1)*32 + g] = e1;
                wbTp[L*1024 + (pb+2)*32 + g] = e2;
                wbTp[L*1024 + (pb+3)*32 + g] = e3;
            }
        } else if (idx < 778) {
            const int c = idx - 768;
            const float4 f = *(const float4*)(w4 + (size_t)c * 256 + 4*lane);
            const u64 e0 = __ballot(f.x >= 0.0f);
            const u64 e1 = __ballot(f.y >= 0.0f);
            const u64 e2 = __ballot(f.z >= 0.0f);
            const u64 e3 = __ballot(f.w >= 0.0f);
            if (lane == 0) {
                w4b[c*4+0] = e0; w4b[c*4+1] = e1; w4b[c*4+2] = e2; w4b[c*4+3] = e3;
            }
        }
    } else {
        for (int i = threadIdx.x; i < 1040; i += 256) { gsum[i] = 0; gsq[i] = 0; }
        if (threadIdx.x < 16) {
            gmin[threadIdx.x] = INT_MAX;
            gmax[threadIdx.x] = INT_MIN;
            colsum[threadIdx.x] = 0.0;
        }
    }
}

// ---------------------------------------------------------------------------
// bn_threshold: exact integer binarization threshold from exact stats.
// ---------------------------------------------------------------------------
__device__ __forceinline__ void bn_threshold(long long sv, long long qv,
    float gaf, float bef, int& sg, int& t)
{
    const double mean = (double)sv / (double)B_ROWS;
    double var = (double)qv / (double)B_ROWS - mean * mean;
    if (var < 0.0) var = 0.0;
    const double rs    = 1.0 / sqrt(var + BN_EPS);
    const double scale = (double)gaf * rs;
    const double bt    = (double)bef;
    if (scale > 0.0) {
        const double tt = fmin(fmax(mean - bt / scale, -1e6), 1e6);
        sg = 1; t = (int)ceil(tt);
    } else if (scale < 0.0) {
        const double tt = fmin(fmax(mean - bt / scale, -1e6), 1e6);
        sg = -1; t = (int)(-floor(tt));
    } else { sg = 0; t = (bt >= 0.0) ? INT_MIN : 1; }
}

// ---------------------------------------------------------------------------
// gemm_coal: 128 rows x 256 cols popcount GEMM (512 thr), coalesced v stores.
// (R7/R11/R14-proven.) ct=tid&31 cols 8ct..+7; rt=tid>>5 rows rt+16j.
// ---------------------------------------------------------------------------
template<int KW>
__device__ __forceinline__ void gemm_coal(const u64* __restrict__ sA,
    const u64* __restrict__ sWp, int K, int row0,
    short* __restrict__ vout, long long* gsumL, long long* gsqL,
    int* sS, int* sQ)
{
    const int tid = threadIdx.x;
    const int ct  = tid & 31;
    const int rt  = tid >> 5;          // 0..15

    unsigned p2[8][4];                 // [row j][colpair e2]
#pragma unroll
    for (int j = 0; j < 8; ++j)
#pragma unroll
        for (int e2 = 0; e2 < 4; ++e2) p2[j][e2] = 0;

#pragma unroll 1
    for (int k = 0; k < KW; ++k) {
        u64 a[8];
#pragma unroll
        for (int j = 0; j < 8; ++j) a[j] = sA[k*128 + rt + 16*j];
        u64 w[8];
#pragma unroll
        for (int e = 0; e < 8; ++e) w[e] = sWp[(e*KW + k)*32 + ct];
#pragma unroll
        for (int j = 0; j < 8; ++j)
#pragma unroll
            for (int e2 = 0; e2 < 4; ++e2)
                p2[j][e2] += (unsigned)__popcll(a[j] ^ w[2*e2])
                           + ((unsigned)__popcll(a[j] ^ w[2*e2+1]) << 16);
    }

    int s8[8], q8[8];
#pragma unroll
    for (int e = 0; e < 8; ++e) { s8[e] = 0; q8[e] = 0; }

#pragma unroll
    for (int j = 0; j < 8; ++j) {
        const int r = row0 + rt + 16*j;
        unsigned pk[4];
#pragma unroll
        for (int e2 = 0; e2 < 4; ++e2) {
            const int v0 = K - 2 * (int)(p2[j][e2] & 0xFFFFu);
            const int v1 = K - 2 * (int)(p2[j][e2] >> 16);
            s8[2*e2]   += v0; q8[2*e2]   += v0*v0;
            s8[2*e2+1] += v1; q8[2*e2+1] += v1*v1;
            pk[e2] = (unsigned)(unsigned short)(short)v0
                   | ((unsigned)(unsigned short)(short)v1 << 16);
        }
        *(uint4*)(vout + (size_t)r * 256 + 8*ct) = make_uint4(pk[0], pk[1], pk[2], pk[3]);
    }

#pragma unroll
    for (int e = 0; e < 8; ++e) {
        s8[e] += __shfl_xor(s8[e], 32);
        q8[e] += __shfl_xor(q8[e], 32);
    }
    if ((tid & 63) < 32) {
#pragma unroll
        for (int e = 0; e < 8; ++e) {
            atomicAdd(&sS[8*ct + e], s8[e]);
            atomicAdd(&sQ[8*ct + e], q8[e]);
        }
    }
    __syncthreads();
    if (tid < 256) {
        atomicAdd((u64*)&gsumL[tid], (u64)(long long)sS[tid]);
        atomicAdd((u64*)&gsqL[tid],  (u64)(long long)sQ[tid]);
    }
}

// ---------------------------------------------------------------------------
// layer0_kernel: stage bitsx tile + w0 e-planes, GEMM, stats, coalesced v.
// (R7/R11/R14-proven, unchanged.)
// ---------------------------------------------------------------------------
__global__ __launch_bounds__(512, 4) void layer0_kernel(
    const u64* __restrict__ bitsx, const u64* __restrict__ wb0p,
    short* __restrict__ v, long long* gsum, long long* gsq)
{
    __shared__ __align__(16) u64 sA[13*128];
    __shared__ __align__(16) u64 sWp[13*8*32];
    __shared__ int sS[256], sQ[256];
    const int tid  = threadIdx.x;
    const int row0 = blockIdx.x * 128;
    for (int i = tid; i < 13*128; i += 512)
        sA[i] = bitsx[(size_t)(i >> 7)*65536 + row0 + (i & 127)];
    for (int i = tid; i < 13*8*32; i += 512) sWp[i] = wb0p[i];
    if (tid < 256) { sS[tid] = 0; sQ[tid] = 0; }
    __syncthreads();
    gemm_coal<13>(sA, sWp, 784, row0, v, gsum, gsq, sS, sQ);
}

// ---------------------------------------------------------------------------
// layer_mid_kernel (R11-proven config): 128 rows, 512 thr, 512 blocks.
// thresholds (redundant/block, exact) -> rebinarize v in-LDS -> GEMM ->
// stats -> v in place.
// ---------------------------------------------------------------------------
__global__ __launch_bounds__(512, 4) void layer_mid_kernel(
    short* v,
    const long long* __restrict__ gsumP, const long long* __restrict__ gsqP,
    const float* __restrict__ gaP, const float* __restrict__ beP,
    const u64* __restrict__ wbTpL, long long* gsumC, long long* gsqC)
{
    __shared__ __align__(16) u64 sA[4*128];
    __shared__ __align__(16) u64 sWp[4*8*32];
    __shared__ int sSgn[256], sThr[256];
    __shared__ int sS[256], sQ[256];
    const int tid  = threadIdx.x;
    const int lane = tid & 63;
    const int wv   = tid >> 6;
    const int row0 = blockIdx.x * 128;

    for (int i = tid; i < 4*8*32; i += 512) sWp[i] = wbTpL[i];
    if (tid < 256) {
        int sg, t;
        bn_threshold(gsumP[tid], gsqP[tid], gaP[tid], beP[tid], sg, t);
        sSgn[tid] = sg; sThr[tid] = t;
        sS[tid] = 0; sQ[tid] = 0;
    }
    __syncthreads();

    const int4 sg4 = *(const int4*)&sSgn[4*lane];
    const int4 th4 = *(const int4*)&sThr[4*lane];
    for (int i = 0; i < 16; ++i) {
        const int r = wv * 16 + i;
        const short4 vv = *(const short4*)(v + (size_t)(row0 + r)*256 + 4*lane);
        const u64 e0 = __ballot(sg4.x * (int)vv.x >= th4.x);
        const u64 e1 = __ballot(sg4.y * (int)vv.y >= th4.y);
        const u64 e2 = __ballot(sg4.z * (int)vv.z >= th4.z);
        const u64 e3 = __ballot(sg4.w * (int)vv.w >= th4.w);
        if (lane == 0) {
            sA[0*128 + r] = e0; sA[1*128 + r] = e1;
            sA[2*128 + r] = e2; sA[3*128 + r] = e3;
        }
    }
    __syncthreads();
    gemm_coal<4>(sA, sWp, 256, row0, v, gsumC, gsqC, sS, sQ);
}

// ---------------------------------------------------------------------------
// layer4_kernel v2 (R7/R11/R14-proven): 512 x 512 = 4096 waves, 16 rows/wave,
// no LDS round-trip: ballots -> lane c<10 popcounts class c -> v4 + stats.
// ---------------------------------------------------------------------------
__global__ __launch_bounds__(512) void layer4_kernel(
    const short* __restrict__ v,
    const long long* __restrict__ gsumP, const long long* __restrict__ gsqP,
    const float* __restrict__ gaP, const float* __restrict__ beP,
    const u64* __restrict__ w4b, short* __restrict__ v4,
    long long* gsum4, long long* gsq4, int* gmin, int* gmax)
{
    __shared__ int sSgn[256], sThr[256];
    __shared__ int sS[10], sQ[10], sMn[10], sMx[10];
    const int tid  = threadIdx.x;
    const int lane = tid & 63;
    const int wv   = tid >> 6;          // 0..7

    if (tid < 256) {
        int sg, t;
        bn_threshold(gsumP[tid], gsqP[tid], gaP[tid], beP[tid], sg, t);
        sSgn[tid] = sg; sThr[tid] = t;
    }
    if (tid < 10) { sS[tid] = 0; sQ[tid] = 0; sMn[tid] = INT_MAX; sMx[tid] = INT_MIN; }
    __syncthreads();

    const int4 sg4 = *(const int4*)&sSgn[4*lane];
    const int4 th4 = *(const int4*)&sThr[4*lane];

    u64 wc0 = 0, wc1 = 0, wc2 = 0, wc3 = 0;
    if (lane < 10) {
        wc0 = w4b[lane*4+0]; wc1 = w4b[lane*4+1];
        wc2 = w4b[lane*4+2]; wc3 = w4b[lane*4+3];
    }

    int accS = 0, accQ = 0, mn = INT_MAX, mx = INT_MIN;
    const int waveId = blockIdx.x * 8 + wv;           // 0..4095
    const int r0 = waveId * 16;
#pragma unroll 2
    for (int i = 0; i < 16; ++i) {
        const int r = r0 + i;
        const short4 vv = *(const short4*)(v + (size_t)r*256 + 4*lane);
        const u64 e0 = __ballot(sg4.x * (int)vv.x >= th4.x);
        const u64 e1 = __ballot(sg4.y * (int)vv.y >= th4.y);
        const u64 e2 = __ballot(sg4.z * (int)vv.z >= th4.z);
        const u64 e3 = __ballot(sg4.w * (int)vv.w >= th4.w);
        if (lane < 10) {
            const int p = (int)__popcll(e0 ^ wc0) + (int)__popcll(e1 ^ wc1)
                        + (int)__popcll(e2 ^ wc2) + (int)__popcll(e3 ^ wc3);
            const int vr = 256 - 2*p;
            v4[(size_t)r*10 + lane] = (short)vr;
            accS += vr; accQ += vr*vr;
            mn = min(mn, vr); mx = max(mx, vr);
        }
    }
    if (lane < 10) {
        atomicAdd(&sS[lane], accS);
        atomicAdd(&sQ[lane], accQ);
        atomicMin(&sMn[lane], mn);
        atomicMax(&sMx[lane], mx);
    }
    __syncthreads();
    if (tid < 10) {
        atomicAdd((u64*)&gsum4[tid], (u64)(long long)sS[tid]);
        atomicAdd((u64*)&gsq4[tid],  (u64)(long long)sQ[tid]);
        atomicMin(&gmin[tid], sMn[tid]);
        atomicMax(&gmax[tid], sMx[tid]);
    }
}

// ---------------------------------------------------------------------------
// colsum_kernel: zs/zb (exact from integer min/max) + partial exp-sums.
// ---------------------------------------------------------------------------
__global__ __launch_bounds__(256) void colsum_kernel(
    const short* __restrict__ v4,
    const long long* __restrict__ gsum4, const long long* __restrict__ gsq4,
    const int* __restrict__ gmin, const int* __restrict__ gmax,
    const float* __restrict__ g4, const float* __restrict__ b4,
    double* zsg, double* zbg, double* colsum)
{
    __shared__ double sred[256];
    __shared__ double sZ[2];
    const int c     = blockIdx.x % 10;
    const int chunk = blockIdx.x / 10;
    const int tid   = threadIdx.x;
    if (tid == 0) {
        const double mean = (double)gsum4[c] / (double)B_ROWS;
        double var = (double)gsq4[c] / (double)B_ROWS - mean * mean;
        if (var < 0.0) var = 0.0;
        const double rs    = 1.0 / sqrt(var + BN_EPS);
        const double scale = (double)g4[c] * rs;
        const double bias  = (double)b4[c] - mean * scale;
        const double z1 = scale * (double)gmin[c] + bias;
        const double z2 = scale * (double)gmax[c] + bias;
        const double zb = bias - fmax(z1, z2);
        sZ[0] = scale; sZ[1] = zb;
        zsg[c] = scale; zbg[c] = zb;       // redundant identical writes, benign
    }
    __syncthreads();
    const double zs = sZ[0], zb = sZ[1];
    double acc = 0.0;
    const int r0 = chunk * 1024;
#pragma unroll
    for (int j = 0; j < 4; ++j) {
        const int r = r0 + j*256 + tid;
        acc += (double)expf((float)(zs * (double)v4[(size_t)r*10 + c] + zb));
    }
    sred[tid] = acc; __syncthreads();
    for (int s = 128; s > 0; s >>= 1) {
        if (tid < s) sred[tid] += sred[tid + s];
        __syncthreads();
    }
    if (tid == 0) atomicAdd(&colsum[c], sred[0]);
}

// ---------------------------------------------------------------------------
// out_kernel: out = expf(zs*v + zb) / colsum, coalesced.
// ---------------------------------------------------------------------------
__global__ __launch_bounds__(256) void out_kernel(
    const short* __restrict__ v4, const double* __restrict__ zsg,
    const double* __restrict__ zbg, const double* __restrict__ colsum,
    float* __restrict__ out)
{
    const int idx = blockIdx.x * 256 + threadIdx.x;
    if (idx >= B_ROWS * 10) return;
    const int c = idx % 10;
    const float e = expf((float)(zsg[c] * (double)v4[idx] + zbg[c]));
    out[idx] = (float)((double)e / colsum[c]);
}

// ---------------------------------------------------------------------------
extern "C" void kernel_launch(void* const* d_in, const int* in_sizes, int n_in,
                              void* d_out, int out_size, void* d_ws, size_t ws_size,
                              hipStream_t stream)
{
    const float* x  = (const float*)d_in[0];
    const float* w0 = (const float*)d_in[1];
    const float* g0 = (const float*)d_in[2];
    const float* b0 = (const float*)d_in[3];
    const float* w1 = (const float*)d_in[4];
    const float* g1 = (const float*)d_in[5];
    const float* b1 = (const float*)d_in[6];
    const float* w2 = (const float*)d_in[7];
    const float* g2 = (const float*)d_in[8];
    const float* b2 = (const float*)d_in[9];
    const float* w3 = (const float*)d_in[10];
    const float* g3 = (const float*)d_in[11];
    const float* b3 = (const float*)d_in[12];
    const float* w4 = (const float*)d_in[13];
    const float* g4 = (const float*)d_in[14];
    const float* b4 = (const float*)d_in[15];

    char* p = (char*)d_ws;
    auto alloc = [&](size_t bytes) -> char* {
        char* r = p;
        p += (bytes + 255) & ~(size_t)255;
        return r;
    };
    u64*       bitsx  = (u64*)alloc(13ull*65536*8);
    u64*       wb0p   = (u64*)alloc(13*8*32*8);
    u64*       wbTp   = (u64*)alloc(3*1024*8);
    u64*       w4b    = (u64*)alloc(40*8);
    short*     v      = (short*)alloc(65536ull*256*2);
    short*     v4     = (short*)alloc(65536ull*10*2);
    long long* gsum   = (long long*)alloc(1040*8);
    long long* gsq    = (long long*)alloc(1040*8);
    int*       gmin   = (int*)alloc(16*4);
    int*       gmax   = (int*)alloc(16*4);
    double*    colsum = (double*)alloc(16*8);
    double*    zsg    = (double*)alloc(16*8);
    double*    zbg    = (double*)alloc(16*8);
    float*     out    = (float*)d_out;

    long long* gsum4 = gsum + 1024;
    long long* gsq4  = gsq  + 1024;

    prep_all<<<8452, 256, 0, stream>>>(x, w0, w1, w2, w3, w4,
                                       bitsx, wb0p, wbTp, w4b,
                                       gsum, gsq, gmin, gmax, colsum);

    layer0_kernel<<<512, 512, 0, stream>>>(bitsx, wb0p, v, gsum, gsq);

    layer_mid_kernel<<<512, 512, 0, stream>>>(v, gsum, gsq, g0, b0,
                                              wbTp + 0*1024, gsum + 256, gsq + 256);
    layer_mid_kernel<<<512, 512, 0, stream>>>(v, gsum + 256, gsq + 256, g1, b1,
                                              wbTp + 1*1024, gsum + 512, gsq + 512);
    layer_mid_kernel<<<512, 512, 0, stream>>>(v, gsum + 512, gsq + 512, g2, b2,
                                              wbTp + 2*1024, gsum + 768, gsq + 768);

    layer4_kernel<<<512, 512, 0, stream>>>(v, gsum + 768, gsq + 768, g3, b3,
                                           w4b, v4, gsum4, gsq4, gmin, gmax);

    colsum_kernel<<<640, 256, 0, stream>>>(v4, gsum4, gsq4, gmin, gmax, g4, b4,
                                           zsg, zbg, colsum);

    out_kernel<<<2560, 256, 0, stream>>>(v4, zsg, zbg, colsum, out);
}